// Round 5
// baseline (809.202 us; speedup 1.0000x reference)
//
#include <hip/hip_runtime.h>
#include <math.h>

// Problem constants
#define BB 4
#define NN 1000
#define TT 8
#define FF 64
#define HH 64
#define NHEADS 4
#define EE 16000
#define E2 17000          // EE + NN self-loops (EXACT per-graph edge total)
#define GG (BB*TT)        // 32 graphs
#define GN (GG*NN)        // 32000 (graph,node) pairs
#define NROWS (BB*NN)     // 4000 GRU rows

// ---------------- helpers ----------------
__device__ __forceinline__ float sigmoidf_(float x) {
    return 1.f / (1.f + __expf(-x));
}
__device__ __forceinline__ float tanhf_(float x) {
    x = fminf(fmaxf(x, -15.f), 15.f);
    float e = __expf(2.f * x);
    return (e - 1.f) / (e + 1.f);
}
__device__ __forceinline__ float leaky_(float x) {
    return (x > 0.f) ? x : 0.2f * x;
}

// ---------------- CSR build ----------------
__global__ void count_edges(const int* __restrict__ ei, int* __restrict__ counts) {
    int g = blockIdx.y;
    int e = blockIdx.x * 256 + threadIdx.x;
    if (e >= E2) return;
    int dst;
    if (e < EE) dst = ei[(size_t)g * 2 * EE + EE + e];
    else        dst = e - EE;   // self-loop
    atomicAdd(&counts[g * NN + dst], 1);
}

// Per-graph scan: each graph owns csr region [g*E2, (g+1)*E2); only a
// 1000-element scan per graph is needed. One 256-thread block per graph.
__global__ __launch_bounds__(256) void scan_offsets_pg(const int* __restrict__ counts,
                                                       int* __restrict__ offs) {
    __shared__ int tot[256];
    int g = blockIdx.x;
    int tid = threadIdx.x;
    int base = tid * 4;
    int c0 = 0, c1 = 0, c2 = 0, c3 = 0;
    if (base < NN) {
        int4 v = *(const int4*)(counts + (size_t)g * NN + base);  // 16B aligned (NN%4==0)
        c0 = v.x; c1 = v.y; c2 = v.z; c3 = v.w;
    }
    int s = c0 + c1 + c2 + c3;
    tot[tid] = s;
    __syncthreads();
    // Hillis-Steele inclusive scan over 256 partials
    for (int off = 1; off < 256; off <<= 1) {
        int y = (tid >= off) ? tot[tid - off] : 0;
        __syncthreads();
        tot[tid] += y;
        __syncthreads();
    }
    int run = g * E2 + tot[tid] - s;  // exclusive prefix + graph base
    if (base < NN) {
        int4 o;
        o.x = run; run += c0;
        o.y = run; run += c1;
        o.z = run; run += c2;
        o.w = run;
        *(int4*)(offs + (size_t)g * NN + base) = o;
    }
    if (g == 0 && tid == 0) offs[GN] = GG * E2;
}

__global__ void scatter_edges(const int* __restrict__ ei, const int* __restrict__ offs,
                              int* __restrict__ cursor, int* __restrict__ csr) {
    int g = blockIdx.y;
    int e = blockIdx.x * 256 + threadIdx.x;
    if (e >= E2) return;
    int src, dst;
    if (e < EE) {
        src = ei[(size_t)g * 2 * EE + e];
        dst = ei[(size_t)g * 2 * EE + EE + e];
    } else {
        src = dst = e - EE;
    }
    int i = g * NN + dst;
    int pos = offs[i] + atomicAdd(&cursor[i], 1);
    csr[pos] = src;
}

// Register pin (used by gru_gi; kept frozen there)
#define PIN64_(arr)                                        \
    _Pragma("unroll")                                      \
    for (int _pi = 0; _pi < 64; ++_pi)                     \
        asm volatile("" : "+v"((arr)[_pi]));

// ---------------- GAT linear (v7: 4-cols-per-lane, 1-wave blocks) ----------------
// R1-R4 lesson: 64-value weight residency is unobtainable (compiler always
// streams; VGPR stayed 44 in 5 structures). v7 makes STREAMING cheap instead:
// lane l owns W columns 4l..4l+3 -> one fully-coalesced float4 load per W row
// (wave covers the whole 1KB row in 1 transaction), shared across ROWS=10
// rows => 40 FMAs per weight load, only 4 w-float4s live. x rows block-uniform
// -> s_load. Head reduce: 4 shuffle levels over 16-lane groups (was 6 over 64).
// hlin slot for col c: 4*(c&63)+(c>>6) = 16*(l&15)+4*j+(l>>4)  — layout unchanged.
// MODE 0: input x [B,N,T,F] gathered per graph g=(b,t).  MODE 1: input [G,N,F] contiguous.
template <int MODE>
__global__ __launch_bounds__(64, 3) void gat_linear(
    const float* __restrict__ in, const float* __restrict__ W,
    const float* __restrict__ att_s, const float* __restrict__ att_d,
    float* __restrict__ hlin, float* __restrict__ asrc, float* __restrict__ adst) {
    const int ROWS = 10;
    const int CH = NN / ROWS;  // 100 -> 3200 blocks (1 wave each)
    int g = blockIdx.x / CH;
    int n0 = (blockIdx.x % CH) * ROWS;
    int l = threadIdx.x;       // 0..63
    int h = l >> 4, m = l & 15;
    int b = g / TT, t = g % TT;

    const float4* W4 = (const float4*)W;   // W4[f*64 + l] = W[f][4l..4l+3]
    float4 as4 = *(const float4*)(att_s + h * 64 + 4 * m);
    float4 ad4 = *(const float4*)(att_d + h * 64 + 4 * m);

    // block-uniform row base pointers -> s_load path
    const float* xr[ROWS];
#pragma unroll
    for (int r = 0; r < ROWS; ++r) {
        int n = n0 + r;
        if (MODE == 0) xr[r] = in + (((size_t)(b * NN + n) * TT + t) * FF);
        else           xr[r] = in + ((size_t)(g * NN + n) * FF);
    }

    float4 acc[ROWS];
#pragma unroll
    for (int r = 0; r < ROWS; ++r) acc[r] = make_float4(0.f, 0.f, 0.f, 0.f);

#pragma unroll
    for (int f4 = 0; f4 < 16; ++f4) {
        // 4 coalesced 1KB weight-row loads (f = 4*f4 + j), 40 FMAs each
        float4 w0 = W4[(4 * f4 + 0) * 64 + l];
        float4 w1 = W4[(4 * f4 + 1) * 64 + l];
        float4 w2 = W4[(4 * f4 + 2) * 64 + l];
        float4 w3 = W4[(4 * f4 + 3) * 64 + l];
#pragma unroll
        for (int r = 0; r < ROWS; ++r) {
            float4 x4 = *(const float4*)(xr[r] + 4 * f4);   // uniform -> s_load
            acc[r].x = fmaf(x4.x, w0.x, acc[r].x);
            acc[r].y = fmaf(x4.x, w0.y, acc[r].y);
            acc[r].z = fmaf(x4.x, w0.z, acc[r].z);
            acc[r].w = fmaf(x4.x, w0.w, acc[r].w);
            acc[r].x = fmaf(x4.y, w1.x, acc[r].x);
            acc[r].y = fmaf(x4.y, w1.y, acc[r].y);
            acc[r].z = fmaf(x4.y, w1.z, acc[r].z);
            acc[r].w = fmaf(x4.y, w1.w, acc[r].w);
            acc[r].x = fmaf(x4.z, w2.x, acc[r].x);
            acc[r].y = fmaf(x4.z, w2.y, acc[r].y);
            acc[r].z = fmaf(x4.z, w2.z, acc[r].z);
            acc[r].w = fmaf(x4.z, w2.w, acc[r].w);
            acc[r].x = fmaf(x4.w, w3.x, acc[r].x);
            acc[r].y = fmaf(x4.w, w3.y, acc[r].y);
            acc[r].z = fmaf(x4.w, w3.z, acc[r].z);
            acc[r].w = fmaf(x4.w, w3.w, acc[r].w);
        }
    }

    // epilogue: stores + 16-lane-group head reductions
#pragma unroll
    for (int r = 0; r < ROWS; ++r) {
        int node = g * NN + n0 + r;
        float* hrow = hlin + ((size_t)node << 8);
        int s0 = 16 * m + h;          // slot for j=0; j adds 4
        hrow[s0 + 0]  = acc[r].x;
        hrow[s0 + 4]  = acc[r].y;
        hrow[s0 + 8]  = acc[r].z;
        hrow[s0 + 12] = acc[r].w;
        float s1 = acc[r].x * as4.x + acc[r].y * as4.y
                 + acc[r].z * as4.z + acc[r].w * as4.w;
        float s2 = acc[r].x * ad4.x + acc[r].y * ad4.y
                 + acc[r].z * ad4.z + acc[r].w * ad4.w;
#pragma unroll
        for (int off = 1; off < 16; off <<= 1) {
            s1 += __shfl_xor(s1, off, 64);
            s2 += __shfl_xor(s2, off, 64);
        }
        if (m == 0) {
            asrc[(size_t)node * NHEADS + h] = s1;
            adst[(size_t)node * NHEADS + h] = s2;
        }
    }
}

// ---------------- GAT edge softmax + aggregation (v3: 8-way MLP phase B) ----------------
// One wave per destination node. Phase A computes per-edge weights into LDS
// (zero-filled beyond deg). Phase B rounds the edge count up to a multiple of
// 8 (padded edges: p=0, src=0 -> harmless) and issues 8 independent 1KB
// gathers per batch: MLP 1 -> 8 (R8: serial loop was latency-bound, L2 at
// 36% of ceiling, VALUBusy 33%).
__global__ __launch_bounds__(256) void gat_edge(
    const float* __restrict__ hlin, const float* __restrict__ asrc,
    const float* __restrict__ adst, const int* __restrict__ offs,
    const int* __restrict__ csr, const float* __restrict__ bias,
    float* __restrict__ out, int do_relu) {
    __shared__ float pbuf[4][64][4];   // [wave][edge-in-chunk][head]
    __shared__ int   sbuf[4][64];
    __shared__ int   degs[4];
    int tid = threadIdx.x;
    int lane = tid & 63, w = tid >> 6;
    // XCD swizzle: graph g -> XCD g%8 (consecutive blockIdx round-robins XCDs)
    int B = blockIdx.x;
    int x = B & 7, j = B >> 3;             // j in 0..999
    int graph = x + 8 * (j / 250);
    int node = graph * NN + ((j % 250) << 2) + w;
    int beg = offs[node], end = offs[node + 1];
    int deg = end - beg;
    if (lane == 0) degs[w] = deg;
    __syncthreads();
    int maxdeg = max(max(degs[0], degs[1]), max(degs[2], degs[3]));
    int nchunk = (maxdeg + 63) >> 6;

    float4 ad = *(const float4*)(adst + (size_t)node * 4);
    const float* asrc_g = asrc + (size_t)graph * NN * 4;
    const float* hg = hlin + ((size_t)graph * NN << 8);

    float4 acc = make_float4(0.f, 0.f, 0.f, 0.f);
    float4 ssum = make_float4(0.f, 0.f, 0.f, 0.f);
    for (int c = 0; c < nchunk; ++c) {
        int e0 = beg + (c << 6);
        int myedge = e0 + lane;
        float4 p = make_float4(0.f, 0.f, 0.f, 0.f);
        int src = 0;
        if (myedge < end) {
            src = csr[myedge];
            float4 a = *(const float4*)(asrc_g + (size_t)src * 4);
            p.x = __expf(leaky_(a.x + ad.x));
            p.y = __expf(leaky_(a.y + ad.y));
            p.z = __expf(leaky_(a.z + ad.z));
            p.w = __expf(leaky_(a.w + ad.w));
        }
        // butterfly sum of this chunk's weights
        float4 t = p;
#pragma unroll
        for (int off = 1; off < 64; off <<= 1) {
            t.x += __shfl_xor(t.x, off, 64);
            t.y += __shfl_xor(t.y, off, 64);
            t.z += __shfl_xor(t.z, off, 64);
            t.w += __shfl_xor(t.w, off, 64);
        }
        ssum.x += t.x; ssum.y += t.y; ssum.z += t.z; ssum.w += t.w;
        *(float4*)&pbuf[w][lane][0] = p;
        sbuf[w][lane] = src;
        __syncthreads();
        int cnt = end - e0;
        if (cnt > 64) cnt = 64;
        int cnt8 = (cnt + 7) & ~7;         // pad to x8: pbuf/sbuf zero-filled
        for (int e = 0; e < cnt8; e += 8) {
            float4 p0 = *(const float4*)&pbuf[w][e + 0][0];
            float4 p1 = *(const float4*)&pbuf[w][e + 1][0];
            float4 p2 = *(const float4*)&pbuf[w][e + 2][0];
            float4 p3 = *(const float4*)&pbuf[w][e + 3][0];
            float4 p4 = *(const float4*)&pbuf[w][e + 4][0];
            float4 p5 = *(const float4*)&pbuf[w][e + 5][0];
            float4 p6 = *(const float4*)&pbuf[w][e + 6][0];
            float4 p7 = *(const float4*)&pbuf[w][e + 7][0];
            int s0 = sbuf[w][e + 0], s1 = sbuf[w][e + 1];
            int s2 = sbuf[w][e + 2], s3 = sbuf[w][e + 3];
            int s4 = sbuf[w][e + 4], s5 = sbuf[w][e + 5];
            int s6 = sbuf[w][e + 6], s7 = sbuf[w][e + 7];
            int lo = lane << 2;
            float4 h0 = *(const float4*)(hg + (((size_t)s0) << 8) + lo);
            float4 h1 = *(const float4*)(hg + (((size_t)s1) << 8) + lo);
            float4 h2 = *(const float4*)(hg + (((size_t)s2) << 8) + lo);
            float4 h3 = *(const float4*)(hg + (((size_t)s3) << 8) + lo);
            float4 h4 = *(const float4*)(hg + (((size_t)s4) << 8) + lo);
            float4 h5 = *(const float4*)(hg + (((size_t)s5) << 8) + lo);
            float4 h6 = *(const float4*)(hg + (((size_t)s6) << 8) + lo);
            float4 h7 = *(const float4*)(hg + (((size_t)s7) << 8) + lo);
            acc.x = fmaf(p0.x, h0.x, acc.x); acc.y = fmaf(p0.y, h0.y, acc.y);
            acc.z = fmaf(p0.z, h0.z, acc.z); acc.w = fmaf(p0.w, h0.w, acc.w);
            acc.x = fmaf(p1.x, h1.x, acc.x); acc.y = fmaf(p1.y, h1.y, acc.y);
            acc.z = fmaf(p1.z, h1.z, acc.z); acc.w = fmaf(p1.w, h1.w, acc.w);
            acc.x = fmaf(p2.x, h2.x, acc.x); acc.y = fmaf(p2.y, h2.y, acc.y);
            acc.z = fmaf(p2.z, h2.z, acc.z); acc.w = fmaf(p2.w, h2.w, acc.w);
            acc.x = fmaf(p3.x, h3.x, acc.x); acc.y = fmaf(p3.y, h3.y, acc.y);
            acc.z = fmaf(p3.z, h3.z, acc.z); acc.w = fmaf(p3.w, h3.w, acc.w);
            acc.x = fmaf(p4.x, h4.x, acc.x); acc.y = fmaf(p4.y, h4.y, acc.y);
            acc.z = fmaf(p4.z, h4.z, acc.z); acc.w = fmaf(p4.w, h4.w, acc.w);
            acc.x = fmaf(p5.x, h5.x, acc.x); acc.y = fmaf(p5.y, h5.y, acc.y);
            acc.z = fmaf(p5.z, h5.z, acc.z); acc.w = fmaf(p5.w, h5.w, acc.w);
            acc.x = fmaf(p6.x, h6.x, acc.x); acc.y = fmaf(p6.y, h6.y, acc.y);
            acc.z = fmaf(p6.z, h6.z, acc.z); acc.w = fmaf(p6.w, h6.w, acc.w);
            acc.x = fmaf(p7.x, h7.x, acc.x); acc.y = fmaf(p7.y, h7.y, acc.y);
            acc.z = fmaf(p7.z, h7.z, acc.z); acc.w = fmaf(p7.w, h7.w, acc.w);
        }
        __syncthreads();
    }
    float o = 0.25f * (acc.x / ssum.x + acc.y / ssum.y + acc.z / ssum.z + acc.w / ssum.w)
            + bias[lane];
    if (do_relu) o = fmaxf(o, 0.f);
    out[((size_t)node << 6) + lane] = o;
}

// ---------------- GRU input-side GEMM: giseq[t][r][192] = bih + x_t[r] @ Wih^T ----------------
// v3: W pinned register-resident (asm), launch_bounds(192,4), 3200 blocks,
// 2-row ILP pairs, float4 x loads.
// MODE 0: input gat2out [G][N][64] gathered (g=b*T+t, row=(b,n)).  MODE 1: input [T][4000][64] flat.
template <int MODE>
__global__ __launch_bounds__(192, 4) void gru_gi(
    const float* __restrict__ in, const float* __restrict__ Wih,
    const float* __restrict__ bih, float* __restrict__ giseq) {
    const int ROWS = 10;  // 3200 blocks * 10 = 32000 (t,row) pairs
    int j = threadIdx.x;  // 0..191
    float wrow[64];
#pragma unroll
    for (int f4 = 0; f4 < 16; ++f4) {
        float4 w = *(const float4*)(Wih + (size_t)j * 64 + f4 * 4);
        wrow[4 * f4 + 0] = w.x; wrow[4 * f4 + 1] = w.y;
        wrow[4 * f4 + 2] = w.z; wrow[4 * f4 + 3] = w.w;
    }
    PIN64_(wrow)
    float bj = bih[j];
    int q0 = blockIdx.x * ROWS;
    int t = q0 / NROWS;            // constant per block (NROWS % ROWS == 0)
    int r0 = q0 - t * NROWS;
    for (int rr = 0; rr < ROWS; rr += 2) {
        const float *xa, *xb;
        if (MODE == 0) {
            int ra = r0 + rr, rb = ra + 1;
            int ba = ra / NN, na = ra - ba * NN;
            int bb2 = rb / NN, nb = rb - bb2 * NN;
            xa = in + (((size_t)(ba * TT + t) * NN + na) << 6);
            xb = in + (((size_t)(bb2 * TT + t) * NN + nb) << 6);
        } else {
            xa = in + ((size_t)(q0 + rr) << 6);
            xb = xa + 64;
        }
        float acca = bj, accb = bj;
#pragma unroll
        for (int f4 = 0; f4 < 16; ++f4) {
            float4 a4 = *(const float4*)(xa + f4 * 4);
            float4 b4 = *(const float4*)(xb + f4 * 4);
            acca = fmaf(a4.x, wrow[4 * f4 + 0], acca);
            acca = fmaf(a4.y, wrow[4 * f4 + 1], acca);
            acca = fmaf(a4.z, wrow[4 * f4 + 2], acca);
            acca = fmaf(a4.w, wrow[4 * f4 + 3], acca);
            accb = fmaf(b4.x, wrow[4 * f4 + 0], accb);
            accb = fmaf(b4.y, wrow[4 * f4 + 1], accb);
            accb = fmaf(b4.z, wrow[4 * f4 + 2], accb);
            accb = fmaf(b4.w, wrow[4 * f4 + 3], accb);
        }
        giseq[(size_t)(q0 + rr) * 192 + j] = acca;
        giseq[(size_t)(q0 + rr + 1) * 192 + j] = accb;
    }
}

// ---------------- GRU recurrence v2 (Whh side only; gi precomputed) ----------------
// Thread ch owns the full gate triplet: Whh rows {ch, 64+ch, 128+ch} in 192 VGPRs.
// h-state in LDS, wave-private (wave w owns rows w*4..w*4+3) -> ZERO barriers.
// h reads are wave-uniform ds_read_b128 broadcasts (16 per row).
// LAYER 0: outseq = h1seq [T][4000][64] (store every t). LAYER 1: outseq = hT [4000][64].
template <int LAYER>
__global__ __launch_bounds__(128) void gru_rec(
    const float* __restrict__ giseq, const float* __restrict__ Whh,
    const float* __restrict__ bhh, float* __restrict__ outseq) {
    __shared__ float hs[8][64];       // 2 waves * 4 rows, wave-private regions
    int tid = threadIdx.x;
    int ch = tid & 63, w = tid >> 6;  // w in {0,1}
    float wr[64], wz[64], wn[64];
#pragma unroll
    for (int k4 = 0; k4 < 16; ++k4) {
        float4 a = *(const float4*)(Whh + (size_t)ch * 64 + k4 * 4);
        float4 b = *(const float4*)(Whh + (size_t)(64 + ch) * 64 + k4 * 4);
        float4 c = *(const float4*)(Whh + (size_t)(128 + ch) * 64 + k4 * 4);
        wr[4*k4+0] = a.x; wr[4*k4+1] = a.y; wr[4*k4+2] = a.z; wr[4*k4+3] = a.w;
        wz[4*k4+0] = b.x; wz[4*k4+1] = b.y; wz[4*k4+2] = b.z; wz[4*k4+3] = b.w;
        wn[4*k4+0] = c.x; wn[4*k4+1] = c.y; wn[4*k4+2] = c.z; wn[4*k4+3] = c.w;
    }
    float br = bhh[ch], bz = bhh[64 + ch], bn = bhh[128 + ch];
    int row0 = blockIdx.x * 8 + w * 4;
    float hprev[4];
#pragma unroll
    for (int r = 0; r < 4; ++r) { hs[w * 4 + r][ch] = 0.f; hprev[r] = 0.f; }

    for (int t = 0; t < TT; ++t) {
#pragma unroll
        for (int r = 0; r < 4; ++r) {
            int row = row0 + r;
            const float* gp = giseq + ((size_t)(t * NROWS + row)) * 192;
            float gir = gp[ch], giz = gp[64 + ch], gin = gp[128 + ch];
            float ar = br, az = bz, an = bn;
#pragma unroll
            for (int k4 = 0; k4 < 16; ++k4) {
                float4 h4 = *(const float4*)&hs[w * 4 + r][k4 * 4];  // broadcast
                ar = fmaf(h4.x, wr[4*k4+0], ar); ar = fmaf(h4.y, wr[4*k4+1], ar);
                ar = fmaf(h4.z, wr[4*k4+2], ar); ar = fmaf(h4.w, wr[4*k4+3], ar);
                az = fmaf(h4.x, wz[4*k4+0], az); az = fmaf(h4.y, wz[4*k4+1], az);
                az = fmaf(h4.z, wz[4*k4+2], az); az = fmaf(h4.w, wz[4*k4+3], az);
                an = fmaf(h4.x, wn[4*k4+0], an); an = fmaf(h4.y, wn[4*k4+1], an);
                an = fmaf(h4.z, wn[4*k4+2], an); an = fmaf(h4.w, wn[4*k4+3], an);
            }
            float rg = sigmoidf_(gir + ar);
            float zg = sigmoidf_(giz + az);
            float ng = tanhf_(gin + rg * an);
            float hnew = (1.f - zg) * ng + zg * hprev[r];
            hprev[r] = hnew;
            hs[w * 4 + r][ch] = hnew;   // same-wave LDS dep, compiler orders via lgkmcnt
            if (LAYER == 0)
                outseq[(((size_t)(t * NROWS + row)) << 6) + ch] = hnew;
        }
    }
    if (LAYER == 1) {
#pragma unroll
        for (int r = 0; r < 4; ++r)
            outseq[(((size_t)(row0 + r)) << 6) + ch] = hprev[r];
    }
}

// ---------------- final MLP ----------------
__global__ __launch_bounds__(64) void mlp_head(
    const float* __restrict__ hT, const float* __restrict__ pW1,
    const float* __restrict__ pb1, const float* __restrict__ pW2,
    const float* __restrict__ pb2, float* __restrict__ out) {
    int r = blockIdx.x, lane = threadIdx.x;
    __shared__ float hrow[64];
    __shared__ float mid[64];
    hrow[lane] = hT[((size_t)r << 6) + lane];
    __syncthreads();
    float acc = pb1[lane];
#pragma unroll
    for (int k = 0; k < 64; ++k) acc = fmaf(hrow[k], pW1[k * 64 + lane], acc);
    mid[lane] = fmaxf(acc, 0.f);
    __syncthreads();
    if (lane < 10) {
        float o = pb2[lane];
#pragma unroll
        for (int k = 0; k < 64; ++k) o = fmaf(mid[k], pW2[k * 10 + lane], o);
        out[(size_t)r * 10 + lane] = o;
    }
}

// ---------------- launch ----------------
extern "C" void kernel_launch(void* const* d_in, const int* in_sizes, int n_in,
                              void* d_out, int out_size, void* d_ws, size_t ws_size,
                              hipStream_t stream) {
    (void)in_sizes; (void)n_in; (void)out_size; (void)ws_size;
    const float* x    = (const float*)d_in[0];
    const int*   ei   = (const int*)d_in[1];
    const float* W1   = (const float*)d_in[3];
    const float* as1  = (const float*)d_in[4];
    const float* ad1  = (const float*)d_in[5];
    const float* b1   = (const float*)d_in[6];
    const float* W2   = (const float*)d_in[7];
    const float* as2  = (const float*)d_in[8];
    const float* ad2  = (const float*)d_in[9];
    const float* b2   = (const float*)d_in[10];
    const float* Wih0 = (const float*)d_in[13];
    const float* Whh0 = (const float*)d_in[14];
    const float* bih0 = (const float*)d_in[15];
    const float* bhh0 = (const float*)d_in[16];
    const float* Wih1 = (const float*)d_in[17];
    const float* Whh1 = (const float*)d_in[18];
    const float* bih1 = (const float*)d_in[19];
    const float* bhh1 = (const float*)d_in[20];
    const float* pW1  = (const float*)d_in[21];
    const float* pb1  = (const float*)d_in[22];
    const float* pW2  = (const float*)d_in[23];
    const float* pb2  = (const float*)d_in[24];
    float* out = (float*)d_out;

    // workspace layout (bytes); overlays noted
    char* ws = (char*)d_ws;
    float* hlin  = (float*)(ws + 0);           // 32,768,000  (overlay: giseq 24.58MB)
    float* giseq = hlin;
    float* asrc  = (float*)(ws + 32768000);    // 512,000     (overlay: hT 1MB spans asrc+adst)
    float* hT    = asrc;
    float* adst  = (float*)(ws + 33280000);    // 512,000
    float* gat1  = (float*)(ws + 33792000);    // 8,192,000   (overlay: h1seq)
    float* h1seq = gat1;
    float* gat2  = (float*)(ws + 41984000);    // 8,192,000
    int* counts  = (int*)(ws + 50176000);      // 128,000
    int* cursor  = (int*)(ws + 50304000);      // 128,000
    int* offs    = (int*)(ws + 50432000);      // 128,004 (padded to 128,256)
    int* csr     = (int*)(ws + 50560256);      // 2,176,000  -> total 52.7MB

    hipMemsetAsync(counts, 0, 2 * GN * sizeof(int), stream);  // counts + cursor (adjacent)

    dim3 egrid((E2 + 255) / 256, GG);
    count_edges<<<egrid, 256, 0, stream>>>(ei, counts);
    scan_offsets_pg<<<GG, 256, 0, stream>>>(counts, offs);
    scatter_edges<<<egrid, 256, 0, stream>>>(ei, offs, cursor, csr);

    gat_linear<0><<<GG * 100, 64, 0, stream>>>(x, W1, as1, ad1, hlin, asrc, adst);
    gat_edge<<<GN / 4, 256, 0, stream>>>(hlin, asrc, adst, offs, csr, b1, gat1, 1);
    gat_linear<1><<<GG * 100, 64, 0, stream>>>(gat1, W2, as2, ad2, hlin, asrc, adst);
    gat_edge<<<GN / 4, 256, 0, stream>>>(hlin, asrc, adst, offs, csr, b2, gat2, 0);

    gru_gi<0><<<3200, 192, 0, stream>>>(gat2, Wih0, bih0, giseq);
    gru_rec<0><<<500, 128, 0, stream>>>(giseq, Whh0, bhh0, h1seq);
    gru_gi<1><<<3200, 192, 0, stream>>>(h1seq, Wih1, bih1, giseq);
    gru_rec<1><<<500, 128, 0, stream>>>(giseq, Whh1, bhh1, hT);

    mlp_head<<<NROWS, 64, 0, stream>>>(hT, pW1, pb1, pW2, pb2, out);
}

// Round 6
// 588.261 us; speedup vs baseline: 1.3756x; 1.3756x over previous
//
#include <hip/hip_runtime.h>
#include <math.h>

// Problem constants
#define BB 4
#define NN 1000
#define TT 8
#define FF 64
#define HH 64
#define NHEADS 4
#define EE 16000
#define E2 17000          // EE + NN self-loops (EXACT per-graph edge total)
#define GG (BB*TT)        // 32 graphs
#define GN (GG*NN)        // 32000 (graph,node) pairs
#define NROWS (BB*NN)     // 4000 GRU rows

// ---------------- helpers ----------------
__device__ __forceinline__ float sigmoidf_(float x) {
    return 1.f / (1.f + __expf(-x));
}
__device__ __forceinline__ float tanhf_(float x) {
    x = fminf(fmaxf(x, -15.f), 15.f);
    float e = __expf(2.f * x);
    return (e - 1.f) / (e + 1.f);
}
__device__ __forceinline__ float leaky_(float x) {
    return (x > 0.f) ? x : 0.2f * x;
}

// ---------------- CSR build ----------------
__global__ void count_edges(const int* __restrict__ ei, int* __restrict__ counts) {
    int g = blockIdx.y;
    int e = blockIdx.x * 256 + threadIdx.x;
    if (e >= E2) return;
    int dst;
    if (e < EE) dst = ei[(size_t)g * 2 * EE + EE + e];
    else        dst = e - EE;   // self-loop
    atomicAdd(&counts[g * NN + dst], 1);
}

// Per-graph scan: each graph owns csr region [g*E2, (g+1)*E2); only a
// 1000-element scan per graph is needed. One 256-thread block per graph.
__global__ __launch_bounds__(256) void scan_offsets_pg(const int* __restrict__ counts,
                                                       int* __restrict__ offs) {
    __shared__ int tot[256];
    int g = blockIdx.x;
    int tid = threadIdx.x;
    int base = tid * 4;
    int c0 = 0, c1 = 0, c2 = 0, c3 = 0;
    if (base < NN) {
        int4 v = *(const int4*)(counts + (size_t)g * NN + base);  // 16B aligned (NN%4==0)
        c0 = v.x; c1 = v.y; c2 = v.z; c3 = v.w;
    }
    int s = c0 + c1 + c2 + c3;
    tot[tid] = s;
    __syncthreads();
    // Hillis-Steele inclusive scan over 256 partials
    for (int off = 1; off < 256; off <<= 1) {
        int y = (tid >= off) ? tot[tid - off] : 0;
        __syncthreads();
        tot[tid] += y;
        __syncthreads();
    }
    int run = g * E2 + tot[tid] - s;  // exclusive prefix + graph base
    if (base < NN) {
        int4 o;
        o.x = run; run += c0;
        o.y = run; run += c1;
        o.z = run; run += c2;
        o.w = run;
        *(int4*)(offs + (size_t)g * NN + base) = o;
    }
    if (g == 0 && tid == 0) offs[GN] = GG * E2;
}

__global__ void scatter_edges(const int* __restrict__ ei, const int* __restrict__ offs,
                              int* __restrict__ cursor, int* __restrict__ csr) {
    int g = blockIdx.y;
    int e = blockIdx.x * 256 + threadIdx.x;
    if (e >= E2) return;
    int src, dst;
    if (e < EE) {
        src = ei[(size_t)g * 2 * EE + e];
        dst = ei[(size_t)g * 2 * EE + EE + e];
    } else {
        src = dst = e - EE;
    }
    int i = g * NN + dst;
    int pos = offs[i] + atomicAdd(&cursor[i], 1);
    csr[pos] = src;
}

// Register pin (used by gru_gi; kept frozen there)
#define PIN64_(arr)                                        \
    _Pragma("unroll")                                      \
    for (int _pi = 0; _pi < 64; ++_pi)                     \
        asm volatile("" : "+v"((arr)[_pi]));

// ---------------- GAT linear (v8: LDS-staged W) ----------------
// R1-R5 lessons: (a) register residency of 64 weights is unobtainable (VGPR
// stuck at 44-84 across 5 structures; compiler always streams); (b) global-
// streamed W leaves the kernel latency-bound at 30-40% VALUBusy; (c) v7's
// lone-wave scatter stores caused write-allocate FETCH explosion (436MB).
// v8: stage all of W (64KB) in LDS once per block (coalesced float4 copy),
// then read wlds[f*256+tid] -> consecutive dwords across lanes = 2-way bank
// aliasing = free. ROWS=20 (1600 blocks) amortizes staging. Store/reduce
// pattern byte-identical to the proven v2 (4 waves cover each hlin line).
// MODE 0: input x [B,N,T,F] gathered per graph g=(b,t).  MODE 1: [G,N,F].
template <int MODE>
__global__ __launch_bounds__(256, 2) void gat_linear(
    const float* __restrict__ in, const float* __restrict__ W,
    const float* __restrict__ att_s, const float* __restrict__ att_d,
    float* __restrict__ hlin, float* __restrict__ asrc, float* __restrict__ adst) {
    const int ROWS = 20;
    const int CH = NN / ROWS;  // 50 -> 1600 blocks
    __shared__ float wlds[FF * 256];   // 64 KB: wlds[f*256 + c] = W[f][c]
    int g = blockIdx.x / CH;
    int n0 = (blockIdx.x % CH) * ROWS;
    int tid = threadIdx.x;

    // cooperative stage: 4096 float4, coalesced, 16 per thread
    {
        const float4* W4 = (const float4*)W;
        float4* L4 = (float4*)wlds;
#pragma unroll
        for (int i = 0; i < 16; ++i) L4[i * 256 + tid] = W4[i * 256 + tid];
    }
    __syncthreads();

    int head = tid >> 6, lane = tid & 63;
    float as = att_s[head * HH + lane];
    float ad = att_d[head * HH + lane];
    int b = g / TT, t = g % TT;

    // block-uniform row base pointers -> scalar loads
    const float* xr[ROWS];
#pragma unroll
    for (int r = 0; r < ROWS; ++r) {
        int n = n0 + r;
        if (MODE == 0) xr[r] = in + (((size_t)(b * NN + n) * TT + t) * FF);
        else           xr[r] = in + ((size_t)(g * NN + n) * FF);
    }

    float acc[ROWS];
#pragma unroll
    for (int r = 0; r < ROWS; ++r) acc[r] = 0.f;

#pragma unroll
    for (int f4 = 0; f4 < 16; ++f4) {
        float w0 = wlds[(4 * f4 + 0) * 256 + tid];   // LDS: 2-way aliasing, free
        float w1 = wlds[(4 * f4 + 1) * 256 + tid];
        float w2 = wlds[(4 * f4 + 2) * 256 + tid];
        float w3 = wlds[(4 * f4 + 3) * 256 + tid];
#pragma unroll
        for (int r = 0; r < ROWS; ++r) {
            float4 x4 = *(const float4*)(xr[r] + 4 * f4);   // uniform -> s_load
            acc[r] = fmaf(x4.x, w0, acc[r]);
            acc[r] = fmaf(x4.y, w1, acc[r]);
            acc[r] = fmaf(x4.z, w2, acc[r]);
            acc[r] = fmaf(x4.w, w3, acc[r]);
        }
    }

    // stores (v2-proven pattern) + batched reductions
    float s1[ROWS], s2[ROWS];
#pragma unroll
    for (int r = 0; r < ROWS; ++r) {
        int n = n0 + r;
        // transposed store: [node][chan=lane][head] — 4 waves cover each line
        hlin[((size_t)(g * NN + n) << 8) + (lane << 2) + head] = acc[r];
        s1[r] = acc[r] * as;
        s2[r] = acc[r] * ad;
    }
#pragma unroll
    for (int off = 32; off; off >>= 1) {
#pragma unroll
        for (int r = 0; r < ROWS; ++r) {
            s1[r] += __shfl_xor(s1[r], off, 64);
            s2[r] += __shfl_xor(s2[r], off, 64);
        }
    }
    if (lane == 0) {
#pragma unroll
        for (int r = 0; r < ROWS; ++r) {
            int n = n0 + r;
            asrc[(size_t)(g * NN + n) * NHEADS + head] = s1[r];
            adst[(size_t)(g * NN + n) * NHEADS + head] = s2[r];
        }
    }
}

// ---------------- GAT edge softmax + aggregation (v3: 8-way MLP phase B) ----------------
// One wave per destination node. Phase A computes per-edge weights into LDS
// (zero-filled beyond deg). Phase B rounds the edge count up to a multiple of
// 8 (padded edges: p=0, src=0 -> harmless) and issues 8 independent 1KB
// gathers per batch: MLP 1 -> 8 (R8: serial loop was latency-bound, L2 at
// 36% of ceiling, VALUBusy 33%).
__global__ __launch_bounds__(256) void gat_edge(
    const float* __restrict__ hlin, const float* __restrict__ asrc,
    const float* __restrict__ adst, const int* __restrict__ offs,
    const int* __restrict__ csr, const float* __restrict__ bias,
    float* __restrict__ out, int do_relu) {
    __shared__ float pbuf[4][64][4];   // [wave][edge-in-chunk][head]
    __shared__ int   sbuf[4][64];
    __shared__ int   degs[4];
    int tid = threadIdx.x;
    int lane = tid & 63, w = tid >> 6;
    // XCD swizzle: graph g -> XCD g%8 (consecutive blockIdx round-robins XCDs)
    int B = blockIdx.x;
    int x = B & 7, j = B >> 3;             // j in 0..999
    int graph = x + 8 * (j / 250);
    int node = graph * NN + ((j % 250) << 2) + w;
    int beg = offs[node], end = offs[node + 1];
    int deg = end - beg;
    if (lane == 0) degs[w] = deg;
    __syncthreads();
    int maxdeg = max(max(degs[0], degs[1]), max(degs[2], degs[3]));
    int nchunk = (maxdeg + 63) >> 6;

    float4 ad = *(const float4*)(adst + (size_t)node * 4);
    const float* asrc_g = asrc + (size_t)graph * NN * 4;
    const float* hg = hlin + ((size_t)graph * NN << 8);

    float4 acc = make_float4(0.f, 0.f, 0.f, 0.f);
    float4 ssum = make_float4(0.f, 0.f, 0.f, 0.f);
    for (int c = 0; c < nchunk; ++c) {
        int e0 = beg + (c << 6);
        int myedge = e0 + lane;
        float4 p = make_float4(0.f, 0.f, 0.f, 0.f);
        int src = 0;
        if (myedge < end) {
            src = csr[myedge];
            float4 a = *(const float4*)(asrc_g + (size_t)src * 4);
            p.x = __expf(leaky_(a.x + ad.x));
            p.y = __expf(leaky_(a.y + ad.y));
            p.z = __expf(leaky_(a.z + ad.z));
            p.w = __expf(leaky_(a.w + ad.w));
        }
        // butterfly sum of this chunk's weights
        float4 t = p;
#pragma unroll
        for (int off = 1; off < 64; off <<= 1) {
            t.x += __shfl_xor(t.x, off, 64);
            t.y += __shfl_xor(t.y, off, 64);
            t.z += __shfl_xor(t.z, off, 64);
            t.w += __shfl_xor(t.w, off, 64);
        }
        ssum.x += t.x; ssum.y += t.y; ssum.z += t.z; ssum.w += t.w;
        *(float4*)&pbuf[w][lane][0] = p;
        sbuf[w][lane] = src;
        __syncthreads();
        int cnt = end - e0;
        if (cnt > 64) cnt = 64;
        int cnt8 = (cnt + 7) & ~7;         // pad to x8: pbuf/sbuf zero-filled
        for (int e = 0; e < cnt8; e += 8) {
            float4 p0 = *(const float4*)&pbuf[w][e + 0][0];
            float4 p1 = *(const float4*)&pbuf[w][e + 1][0];
            float4 p2 = *(const float4*)&pbuf[w][e + 2][0];
            float4 p3 = *(const float4*)&pbuf[w][e + 3][0];
            float4 p4 = *(const float4*)&pbuf[w][e + 4][0];
            float4 p5 = *(const float4*)&pbuf[w][e + 5][0];
            float4 p6 = *(const float4*)&pbuf[w][e + 6][0];
            float4 p7 = *(const float4*)&pbuf[w][e + 7][0];
            int s0 = sbuf[w][e + 0], s1 = sbuf[w][e + 1];
            int s2 = sbuf[w][e + 2], s3 = sbuf[w][e + 3];
            int s4 = sbuf[w][e + 4], s5 = sbuf[w][e + 5];
            int s6 = sbuf[w][e + 6], s7 = sbuf[w][e + 7];
            int lo = lane << 2;
            float4 h0 = *(const float4*)(hg + (((size_t)s0) << 8) + lo);
            float4 h1 = *(const float4*)(hg + (((size_t)s1) << 8) + lo);
            float4 h2 = *(const float4*)(hg + (((size_t)s2) << 8) + lo);
            float4 h3 = *(const float4*)(hg + (((size_t)s3) << 8) + lo);
            float4 h4 = *(const float4*)(hg + (((size_t)s4) << 8) + lo);
            float4 h5 = *(const float4*)(hg + (((size_t)s5) << 8) + lo);
            float4 h6 = *(const float4*)(hg + (((size_t)s6) << 8) + lo);
            float4 h7 = *(const float4*)(hg + (((size_t)s7) << 8) + lo);
            acc.x = fmaf(p0.x, h0.x, acc.x); acc.y = fmaf(p0.y, h0.y, acc.y);
            acc.z = fmaf(p0.z, h0.z, acc.z); acc.w = fmaf(p0.w, h0.w, acc.w);
            acc.x = fmaf(p1.x, h1.x, acc.x); acc.y = fmaf(p1.y, h1.y, acc.y);
            acc.z = fmaf(p1.z, h1.z, acc.z); acc.w = fmaf(p1.w, h1.w, acc.w);
            acc.x = fmaf(p2.x, h2.x, acc.x); acc.y = fmaf(p2.y, h2.y, acc.y);
            acc.z = fmaf(p2.z, h2.z, acc.z); acc.w = fmaf(p2.w, h2.w, acc.w);
            acc.x = fmaf(p3.x, h3.x, acc.x); acc.y = fmaf(p3.y, h3.y, acc.y);
            acc.z = fmaf(p3.z, h3.z, acc.z); acc.w = fmaf(p3.w, h3.w, acc.w);
            acc.x = fmaf(p4.x, h4.x, acc.x); acc.y = fmaf(p4.y, h4.y, acc.y);
            acc.z = fmaf(p4.z, h4.z, acc.z); acc.w = fmaf(p4.w, h4.w, acc.w);
            acc.x = fmaf(p5.x, h5.x, acc.x); acc.y = fmaf(p5.y, h5.y, acc.y);
            acc.z = fmaf(p5.z, h5.z, acc.z); acc.w = fmaf(p5.w, h5.w, acc.w);
            acc.x = fmaf(p6.x, h6.x, acc.x); acc.y = fmaf(p6.y, h6.y, acc.y);
            acc.z = fmaf(p6.z, h6.z, acc.z); acc.w = fmaf(p6.w, h6.w, acc.w);
            acc.x = fmaf(p7.x, h7.x, acc.x); acc.y = fmaf(p7.y, h7.y, acc.y);
            acc.z = fmaf(p7.z, h7.z, acc.z); acc.w = fmaf(p7.w, h7.w, acc.w);
        }
        __syncthreads();
    }
    float o = 0.25f * (acc.x / ssum.x + acc.y / ssum.y + acc.z / ssum.z + acc.w / ssum.w)
            + bias[lane];
    if (do_relu) o = fmaxf(o, 0.f);
    out[((size_t)node << 6) + lane] = o;
}

// ---------------- GRU input-side GEMM: giseq[t][r][192] = bih + x_t[r] @ Wih^T ----------------
// v3: W pinned register-resident (asm), launch_bounds(192,4), 3200 blocks,
// 2-row ILP pairs, float4 x loads.
// MODE 0: input gat2out [G][N][64] gathered (g=b*T+t, row=(b,n)).  MODE 1: input [T][4000][64] flat.
template <int MODE>
__global__ __launch_bounds__(192, 4) void gru_gi(
    const float* __restrict__ in, const float* __restrict__ Wih,
    const float* __restrict__ bih, float* __restrict__ giseq) {
    const int ROWS = 10;  // 3200 blocks * 10 = 32000 (t,row) pairs
    int j = threadIdx.x;  // 0..191
    float wrow[64];
#pragma unroll
    for (int f4 = 0; f4 < 16; ++f4) {
        float4 w = *(const float4*)(Wih + (size_t)j * 64 + f4 * 4);
        wrow[4 * f4 + 0] = w.x; wrow[4 * f4 + 1] = w.y;
        wrow[4 * f4 + 2] = w.z; wrow[4 * f4 + 3] = w.w;
    }
    PIN64_(wrow)
    float bj = bih[j];
    int q0 = blockIdx.x * ROWS;
    int t = q0 / NROWS;            // constant per block (NROWS % ROWS == 0)
    int r0 = q0 - t * NROWS;
    for (int rr = 0; rr < ROWS; rr += 2) {
        const float *xa, *xb;
        if (MODE == 0) {
            int ra = r0 + rr, rb = ra + 1;
            int ba = ra / NN, na = ra - ba * NN;
            int bb2 = rb / NN, nb = rb - bb2 * NN;
            xa = in + (((size_t)(ba * TT + t) * NN + na) << 6);
            xb = in + (((size_t)(bb2 * TT + t) * NN + nb) << 6);
        } else {
            xa = in + ((size_t)(q0 + rr) << 6);
            xb = xa + 64;
        }
        float acca = bj, accb = bj;
#pragma unroll
        for (int f4 = 0; f4 < 16; ++f4) {
            float4 a4 = *(const float4*)(xa + f4 * 4);
            float4 b4 = *(const float4*)(xb + f4 * 4);
            acca = fmaf(a4.x, wrow[4 * f4 + 0], acca);
            acca = fmaf(a4.y, wrow[4 * f4 + 1], acca);
            acca = fmaf(a4.z, wrow[4 * f4 + 2], acca);
            acca = fmaf(a4.w, wrow[4 * f4 + 3], acca);
            accb = fmaf(b4.x, wrow[4 * f4 + 0], accb);
            accb = fmaf(b4.y, wrow[4 * f4 + 1], accb);
            accb = fmaf(b4.z, wrow[4 * f4 + 2], accb);
            accb = fmaf(b4.w, wrow[4 * f4 + 3], accb);
        }
        giseq[(size_t)(q0 + rr) * 192 + j] = acca;
        giseq[(size_t)(q0 + rr + 1) * 192 + j] = accb;
    }
}

// ---------------- GRU recurrence v2 (Whh side only; gi precomputed) ----------------
// Thread ch owns the full gate triplet: Whh rows {ch, 64+ch, 128+ch} in 192 VGPRs.
// h-state in LDS, wave-private (wave w owns rows w*4..w*4+3) -> ZERO barriers.
// h reads are wave-uniform ds_read_b128 broadcasts (16 per row).
// LAYER 0: outseq = h1seq [T][4000][64] (store every t). LAYER 1: outseq = hT [4000][64].
template <int LAYER>
__global__ __launch_bounds__(128) void gru_rec(
    const float* __restrict__ giseq, const float* __restrict__ Whh,
    const float* __restrict__ bhh, float* __restrict__ outseq) {
    __shared__ float hs[8][64];       // 2 waves * 4 rows, wave-private regions
    int tid = threadIdx.x;
    int ch = tid & 63, w = tid >> 6;  // w in {0,1}
    float wr[64], wz[64], wn[64];
#pragma unroll
    for (int k4 = 0; k4 < 16; ++k4) {
        float4 a = *(const float4*)(Whh + (size_t)ch * 64 + k4 * 4);
        float4 b = *(const float4*)(Whh + (size_t)(64 + ch) * 64 + k4 * 4);
        float4 c = *(const float4*)(Whh + (size_t)(128 + ch) * 64 + k4 * 4);
        wr[4*k4+0] = a.x; wr[4*k4+1] = a.y; wr[4*k4+2] = a.z; wr[4*k4+3] = a.w;
        wz[4*k4+0] = b.x; wz[4*k4+1] = b.y; wz[4*k4+2] = b.z; wz[4*k4+3] = b.w;
        wn[4*k4+0] = c.x; wn[4*k4+1] = c.y; wn[4*k4+2] = c.z; wn[4*k4+3] = c.w;
    }
    float br = bhh[ch], bz = bhh[64 + ch], bn = bhh[128 + ch];
    int row0 = blockIdx.x * 8 + w * 4;
    float hprev[4];
#pragma unroll
    for (int r = 0; r < 4; ++r) { hs[w * 4 + r][ch] = 0.f; hprev[r] = 0.f; }

    for (int t = 0; t < TT; ++t) {
#pragma unroll
        for (int r = 0; r < 4; ++r) {
            int row = row0 + r;
            const float* gp = giseq + ((size_t)(t * NROWS + row)) * 192;
            float gir = gp[ch], giz = gp[64 + ch], gin = gp[128 + ch];
            float ar = br, az = bz, an = bn;
#pragma unroll
            for (int k4 = 0; k4 < 16; ++k4) {
                float4 h4 = *(const float4*)&hs[w * 4 + r][k4 * 4];  // broadcast
                ar = fmaf(h4.x, wr[4*k4+0], ar); ar = fmaf(h4.y, wr[4*k4+1], ar);
                ar = fmaf(h4.z, wr[4*k4+2], ar); ar = fmaf(h4.w, wr[4*k4+3], ar);
                az = fmaf(h4.x, wz[4*k4+0], az); az = fmaf(h4.y, wz[4*k4+1], az);
                az = fmaf(h4.z, wz[4*k4+2], az); az = fmaf(h4.w, wz[4*k4+3], az);
                an = fmaf(h4.x, wn[4*k4+0], an); an = fmaf(h4.y, wn[4*k4+1], an);
                an = fmaf(h4.z, wn[4*k4+2], an); an = fmaf(h4.w, wn[4*k4+3], an);
            }
            float rg = sigmoidf_(gir + ar);
            float zg = sigmoidf_(giz + az);
            float ng = tanhf_(gin + rg * an);
            float hnew = (1.f - zg) * ng + zg * hprev[r];
            hprev[r] = hnew;
            hs[w * 4 + r][ch] = hnew;   // same-wave LDS dep, compiler orders via lgkmcnt
            if (LAYER == 0)
                outseq[(((size_t)(t * NROWS + row)) << 6) + ch] = hnew;
        }
    }
    if (LAYER == 1) {
#pragma unroll
        for (int r = 0; r < 4; ++r)
            outseq[(((size_t)(row0 + r)) << 6) + ch] = hprev[r];
    }
}

// ---------------- final MLP ----------------
__global__ __launch_bounds__(64) void mlp_head(
    const float* __restrict__ hT, const float* __restrict__ pW1,
    const float* __restrict__ pb1, const float* __restrict__ pW2,
    const float* __restrict__ pb2, float* __restrict__ out) {
    int r = blockIdx.x, lane = threadIdx.x;
    __shared__ float hrow[64];
    __shared__ float mid[64];
    hrow[lane] = hT[((size_t)r << 6) + lane];
    __syncthreads();
    float acc = pb1[lane];
#pragma unroll
    for (int k = 0; k < 64; ++k) acc = fmaf(hrow[k], pW1[k * 64 + lane], acc);
    mid[lane] = fmaxf(acc, 0.f);
    __syncthreads();
    if (lane < 10) {
        float o = pb2[lane];
#pragma unroll
        for (int k = 0; k < 64; ++k) o = fmaf(mid[k], pW2[k * 10 + lane], o);
        out[(size_t)r * 10 + lane] = o;
    }
}

// ---------------- launch ----------------
extern "C" void kernel_launch(void* const* d_in, const int* in_sizes, int n_in,
                              void* d_out, int out_size, void* d_ws, size_t ws_size,
                              hipStream_t stream) {
    (void)in_sizes; (void)n_in; (void)out_size; (void)ws_size;
    const float* x    = (const float*)d_in[0];
    const int*   ei   = (const int*)d_in[1];
    const float* W1   = (const float*)d_in[3];
    const float* as1  = (const float*)d_in[4];
    const float* ad1  = (const float*)d_in[5];
    const float* b1   = (const float*)d_in[6];
    const float* W2   = (const float*)d_in[7];
    const float* as2  = (const float*)d_in[8];
    const float* ad2  = (const float*)d_in[9];
    const float* b2   = (const float*)d_in[10];
    const float* Wih0 = (const float*)d_in[13];
    const float* Whh0 = (const float*)d_in[14];
    const float* bih0 = (const float*)d_in[15];
    const float* bhh0 = (const float*)d_in[16];
    const float* Wih1 = (const float*)d_in[17];
    const float* Whh1 = (const float*)d_in[18];
    const float* bih1 = (const float*)d_in[19];
    const float* bhh1 = (const float*)d_in[20];
    const float* pW1  = (const float*)d_in[21];
    const float* pb1  = (const float*)d_in[22];
    const float* pW2  = (const float*)d_in[23];
    const float* pb2  = (const float*)d_in[24];
    float* out = (float*)d_out;

    // workspace layout (bytes); overlays noted
    char* ws = (char*)d_ws;
    float* hlin  = (float*)(ws + 0);           // 32,768,000  (overlay: giseq 24.58MB)
    float* giseq = hlin;
    float* asrc  = (float*)(ws + 32768000);    // 512,000     (overlay: hT 1MB spans asrc+adst)
    float* hT    = asrc;
    float* adst  = (float*)(ws + 33280000);    // 512,000
    float* gat1  = (float*)(ws + 33792000);    // 8,192,000   (overlay: h1seq)
    float* h1seq = gat1;
    float* gat2  = (float*)(ws + 41984000);    // 8,192,000
    int* counts  = (int*)(ws + 50176000);      // 128,000
    int* cursor  = (int*)(ws + 50304000);      // 128,000
    int* offs    = (int*)(ws + 50432000);      // 128,004 (padded to 128,256)
    int* csr     = (int*)(ws + 50560256);      // 2,176,000  -> total 52.7MB

    hipMemsetAsync(counts, 0, 2 * GN * sizeof(int), stream);  // counts + cursor (adjacent)

    dim3 egrid((E2 + 255) / 256, GG);
    count_edges<<<egrid, 256, 0, stream>>>(ei, counts);
    scan_offsets_pg<<<GG, 256, 0, stream>>>(counts, offs);
    scatter_edges<<<egrid, 256, 0, stream>>>(ei, offs, cursor, csr);

    gat_linear<0><<<GG * 50, 256, 0, stream>>>(x, W1, as1, ad1, hlin, asrc, adst);
    gat_edge<<<GN / 4, 256, 0, stream>>>(hlin, asrc, adst, offs, csr, b1, gat1, 1);
    gat_linear<1><<<GG * 50, 256, 0, stream>>>(gat1, W2, as2, ad2, hlin, asrc, adst);
    gat_edge<<<GN / 4, 256, 0, stream>>>(hlin, asrc, adst, offs, csr, b2, gat2, 0);

    gru_gi<0><<<3200, 192, 0, stream>>>(gat2, Wih0, bih0, giseq);
    gru_rec<0><<<500, 128, 0, stream>>>(giseq, Whh0, bhh0, h1seq);
    gru_gi<1><<<3200, 192, 0, stream>>>(h1seq, Wih1, bih1, giseq);
    gru_rec<1><<<500, 128, 0, stream>>>(giseq, Whh1, bhh1, hT);

    mlp_head<<<NROWS, 64, 0, stream>>>(hT, pW1, pb1, pW2, pb2, out);
}

// Round 7
// 461.609 us; speedup vs baseline: 1.7530x; 1.2744x over previous
//
#include <hip/hip_runtime.h>
#include <math.h>

// Problem constants
#define BB 4
#define NN 1000
#define TT 8
#define FF 64
#define HH 64
#define NHEADS 4
#define EE 16000
#define E2 17000          // EE + NN self-loops (EXACT per-graph edge total)
#define GG (BB*TT)        // 32 graphs
#define GN (GG*NN)        // 32000 (graph,node) pairs
#define NROWS (BB*NN)     // 4000 GRU rows

// ---------------- helpers ----------------
__device__ __forceinline__ float sigmoidf_(float x) {
    return 1.f / (1.f + __expf(-x));
}
__device__ __forceinline__ float tanhf_(float x) {
    x = fminf(fmaxf(x, -15.f), 15.f);
    float e = __expf(2.f * x);
    return (e - 1.f) / (e + 1.f);
}
__device__ __forceinline__ float leaky_(float x) {
    return (x > 0.f) ? x : 0.2f * x;
}

// ---------------- CSR build ----------------
__global__ void count_edges(const int* __restrict__ ei, int* __restrict__ counts) {
    int g = blockIdx.y;
    int e = blockIdx.x * 256 + threadIdx.x;
    if (e >= E2) return;
    int dst;
    if (e < EE) dst = ei[(size_t)g * 2 * EE + EE + e];
    else        dst = e - EE;   // self-loop
    atomicAdd(&counts[g * NN + dst], 1);
}

// Per-graph scan: each graph owns csr region [g*E2, (g+1)*E2); only a
// 1000-element scan per graph is needed. One 256-thread block per graph.
__global__ __launch_bounds__(256) void scan_offsets_pg(const int* __restrict__ counts,
                                                       int* __restrict__ offs) {
    __shared__ int tot[256];
    int g = blockIdx.x;
    int tid = threadIdx.x;
    int base = tid * 4;
    int c0 = 0, c1 = 0, c2 = 0, c3 = 0;
    if (base < NN) {
        int4 v = *(const int4*)(counts + (size_t)g * NN + base);  // 16B aligned (NN%4==0)
        c0 = v.x; c1 = v.y; c2 = v.z; c3 = v.w;
    }
    int s = c0 + c1 + c2 + c3;
    tot[tid] = s;
    __syncthreads();
    // Hillis-Steele inclusive scan over 256 partials
    for (int off = 1; off < 256; off <<= 1) {
        int y = (tid >= off) ? tot[tid - off] : 0;
        __syncthreads();
        tot[tid] += y;
        __syncthreads();
    }
    int run = g * E2 + tot[tid] - s;  // exclusive prefix + graph base
    if (base < NN) {
        int4 o;
        o.x = run; run += c0;
        o.y = run; run += c1;
        o.z = run; run += c2;
        o.w = run;
        *(int4*)(offs + (size_t)g * NN + base) = o;
    }
    if (g == 0 && tid == 0) offs[GN] = GG * E2;
}

__global__ void scatter_edges(const int* __restrict__ ei, const int* __restrict__ offs,
                              int* __restrict__ cursor, int* __restrict__ csr) {
    int g = blockIdx.y;
    int e = blockIdx.x * 256 + threadIdx.x;
    if (e >= E2) return;
    int src, dst;
    if (e < EE) {
        src = ei[(size_t)g * 2 * EE + e];
        dst = ei[(size_t)g * 2 * EE + EE + e];
    } else {
        src = dst = e - EE;
    }
    int i = g * NN + dst;
    int pos = offs[i] + atomicAdd(&cursor[i], 1);
    csr[pos] = src;
}

// Register pin (used by gru_gi; kept frozen there)
#define PIN64_(arr)                                        \
    _Pragma("unroll")                                      \
    for (int _pi = 0; _pi < 64; ++_pi)                     \
        asm volatile("" : "+v"((arr)[_pi]));

// ---------------- GAT linear (v9: LDS W + LDS x, 512-thread blocks) ----------------
// R5(v8) post-mortem: 64KB LDS at 256 threads -> 2 waves/SIMD, and scalar
// x s_loads serialized against LDS reads on lgkmcnt -> VALUBusy 14%. v9 fixes
// both: 512 threads (2 col-copies) -> 16 waves/CU at the same 2 blocks/CU;
// x staged in LDS -> hot loop is pure LDS+VALU (4 conflict-free W ds_reads +
// 10 broadcast x ds_read_b128 + 40 FMAs per f4 per thread). LDS BW check:
// ~21KB/CU/f4 = 84 clk << 640 clk VALU -> VALU-bound by construction.
// Store/reduce byte-pattern identical to proven v2 (4 head-waves cover each
// hlin line -> no write-allocate explosion; v7 guard).
// MODE 0: input x [B,N,T,F] gathered per graph g=(b,t).  MODE 1: [G,N,F].
template <int MODE>
__global__ __launch_bounds__(512, 4) void gat_linear(
    const float* __restrict__ in, const float* __restrict__ W,
    const float* __restrict__ att_s, const float* __restrict__ att_d,
    float* __restrict__ hlin, float* __restrict__ asrc, float* __restrict__ adst) {
    const int ROWS = 20;
    const int CH = NN / ROWS;          // 50 -> 1600 blocks
    __shared__ float wlds[FF * 256];   // 64 KB: wlds[f*256 + c] = W[f][c]
    __shared__ float xlds[ROWS][FF];   // 5 KB
    int g = blockIdx.x / CH;
    int n0 = (blockIdx.x % CH) * ROWS;
    int tid = threadIdx.x;
    int b = g / TT, t = g % TT;

    // stage W: 4096 float4 over 512 threads = 8 each (coalesced)
    {
        const float4* W4 = (const float4*)W;
        float4* L4 = (float4*)wlds;
#pragma unroll
        for (int i = 0; i < 8; ++i) L4[i * 512 + tid] = W4[i * 512 + tid];
    }
    // stage x: 20 rows x 64 floats; 8 rows per pass, 256B coalesced per wave
    {
        int xr = tid >> 6, xf = tid & 63;
#pragma unroll
        for (int p = 0; p < 3; ++p) {
            int r = p * 8 + xr;
            if (r < ROWS) {
                int n = n0 + r;
                const float* xrow = (MODE == 0)
                    ? in + (((size_t)(b * NN + n) * TT + t) * FF)
                    : in + ((size_t)(g * NN + n) * FF);
                xlds[r][xf] = xrow[xf];
            }
        }
    }
    __syncthreads();

    int c = tid & 255, half = tid >> 8;   // half 0: rows 0-9, half 1: rows 10-19
    int head = c >> 6, lane = c & 63;     // wave w: head = w&3 (uniform per wave)
    float as = att_s[head * HH + lane];
    float ad = att_d[head * HH + lane];

    float acc[10];
#pragma unroll
    for (int r = 0; r < 10; ++r) acc[r] = 0.f;

#pragma unroll
    for (int f4 = 0; f4 < 16; ++f4) {
        float w0 = wlds[(4 * f4 + 0) * 256 + c];   // 2-way bank aliasing: free
        float w1 = wlds[(4 * f4 + 1) * 256 + c];
        float w2 = wlds[(4 * f4 + 2) * 256 + c];
        float w3 = wlds[(4 * f4 + 3) * 256 + c];
#pragma unroll
        for (int r = 0; r < 10; ++r) {
            float4 x4 = *(const float4*)&xlds[half * 10 + r][4 * f4];  // broadcast
            acc[r] = fmaf(x4.x, w0, acc[r]);
            acc[r] = fmaf(x4.y, w1, acc[r]);
            acc[r] = fmaf(x4.z, w2, acc[r]);
            acc[r] = fmaf(x4.w, w3, acc[r]);
        }
    }

    // stores (v2-proven pattern) + batched reductions
    float s1[10], s2[10];
#pragma unroll
    for (int r = 0; r < 10; ++r) {
        int n = n0 + half * 10 + r;
        // transposed store: [node][chan=lane][head] — 4 head-waves cover each line
        hlin[((size_t)(g * NN + n) << 8) + (lane << 2) + head] = acc[r];
        s1[r] = acc[r] * as;
        s2[r] = acc[r] * ad;
    }
#pragma unroll
    for (int off = 32; off; off >>= 1) {
#pragma unroll
        for (int r = 0; r < 10; ++r) {
            s1[r] += __shfl_xor(s1[r], off, 64);
            s2[r] += __shfl_xor(s2[r], off, 64);
        }
    }
    if (lane == 0) {
#pragma unroll
        for (int r = 0; r < 10; ++r) {
            int n = n0 + half * 10 + r;
            asrc[(size_t)(g * NN + n) * NHEADS + head] = s1[r];
            adst[(size_t)(g * NN + n) * NHEADS + head] = s2[r];
        }
    }
}

// ---------------- GAT edge softmax + aggregation (v3: 8-way MLP phase B) ----------------
// One wave per destination node. Phase A computes per-edge weights into LDS
// (zero-filled beyond deg). Phase B rounds the edge count up to a multiple of
// 8 (padded edges: p=0, src=0 -> harmless) and issues 8 independent 1KB
// gathers per batch: MLP 1 -> 8 (R8: serial loop was latency-bound, L2 at
// 36% of ceiling, VALUBusy 33%).
__global__ __launch_bounds__(256) void gat_edge(
    const float* __restrict__ hlin, const float* __restrict__ asrc,
    const float* __restrict__ adst, const int* __restrict__ offs,
    const int* __restrict__ csr, const float* __restrict__ bias,
    float* __restrict__ out, int do_relu) {
    __shared__ float pbuf[4][64][4];   // [wave][edge-in-chunk][head]
    __shared__ int   sbuf[4][64];
    __shared__ int   degs[4];
    int tid = threadIdx.x;
    int lane = tid & 63, w = tid >> 6;
    // XCD swizzle: graph g -> XCD g%8 (consecutive blockIdx round-robins XCDs)
    int B = blockIdx.x;
    int x = B & 7, j = B >> 3;             // j in 0..999
    int graph = x + 8 * (j / 250);
    int node = graph * NN + ((j % 250) << 2) + w;
    int beg = offs[node], end = offs[node + 1];
    int deg = end - beg;
    if (lane == 0) degs[w] = deg;
    __syncthreads();
    int maxdeg = max(max(degs[0], degs[1]), max(degs[2], degs[3]));
    int nchunk = (maxdeg + 63) >> 6;

    float4 ad = *(const float4*)(adst + (size_t)node * 4);
    const float* asrc_g = asrc + (size_t)graph * NN * 4;
    const float* hg = hlin + ((size_t)graph * NN << 8);

    float4 acc = make_float4(0.f, 0.f, 0.f, 0.f);
    float4 ssum = make_float4(0.f, 0.f, 0.f, 0.f);
    for (int c = 0; c < nchunk; ++c) {
        int e0 = beg + (c << 6);
        int myedge = e0 + lane;
        float4 p = make_float4(0.f, 0.f, 0.f, 0.f);
        int src = 0;
        if (myedge < end) {
            src = csr[myedge];
            float4 a = *(const float4*)(asrc_g + (size_t)src * 4);
            p.x = __expf(leaky_(a.x + ad.x));
            p.y = __expf(leaky_(a.y + ad.y));
            p.z = __expf(leaky_(a.z + ad.z));
            p.w = __expf(leaky_(a.w + ad.w));
        }
        // butterfly sum of this chunk's weights
        float4 t = p;
#pragma unroll
        for (int off = 1; off < 64; off <<= 1) {
            t.x += __shfl_xor(t.x, off, 64);
            t.y += __shfl_xor(t.y, off, 64);
            t.z += __shfl_xor(t.z, off, 64);
            t.w += __shfl_xor(t.w, off, 64);
        }
        ssum.x += t.x; ssum.y += t.y; ssum.z += t.z; ssum.w += t.w;
        *(float4*)&pbuf[w][lane][0] = p;
        sbuf[w][lane] = src;
        __syncthreads();
        int cnt = end - e0;
        if (cnt > 64) cnt = 64;
        int cnt8 = (cnt + 7) & ~7;         // pad to x8: pbuf/sbuf zero-filled
        for (int e = 0; e < cnt8; e += 8) {
            float4 p0 = *(const float4*)&pbuf[w][e + 0][0];
            float4 p1 = *(const float4*)&pbuf[w][e + 1][0];
            float4 p2 = *(const float4*)&pbuf[w][e + 2][0];
            float4 p3 = *(const float4*)&pbuf[w][e + 3][0];
            float4 p4 = *(const float4*)&pbuf[w][e + 4][0];
            float4 p5 = *(const float4*)&pbuf[w][e + 5][0];
            float4 p6 = *(const float4*)&pbuf[w][e + 6][0];
            float4 p7 = *(const float4*)&pbuf[w][e + 7][0];
            int s0 = sbuf[w][e + 0], s1 = sbuf[w][e + 1];
            int s2 = sbuf[w][e + 2], s3 = sbuf[w][e + 3];
            int s4 = sbuf[w][e + 4], s5 = sbuf[w][e + 5];
            int s6 = sbuf[w][e + 6], s7 = sbuf[w][e + 7];
            int lo = lane << 2;
            float4 h0 = *(const float4*)(hg + (((size_t)s0) << 8) + lo);
            float4 h1 = *(const float4*)(hg + (((size_t)s1) << 8) + lo);
            float4 h2 = *(const float4*)(hg + (((size_t)s2) << 8) + lo);
            float4 h3 = *(const float4*)(hg + (((size_t)s3) << 8) + lo);
            float4 h4 = *(const float4*)(hg + (((size_t)s4) << 8) + lo);
            float4 h5 = *(const float4*)(hg + (((size_t)s5) << 8) + lo);
            float4 h6 = *(const float4*)(hg + (((size_t)s6) << 8) + lo);
            float4 h7 = *(const float4*)(hg + (((size_t)s7) << 8) + lo);
            acc.x = fmaf(p0.x, h0.x, acc.x); acc.y = fmaf(p0.y, h0.y, acc.y);
            acc.z = fmaf(p0.z, h0.z, acc.z); acc.w = fmaf(p0.w, h0.w, acc.w);
            acc.x = fmaf(p1.x, h1.x, acc.x); acc.y = fmaf(p1.y, h1.y, acc.y);
            acc.z = fmaf(p1.z, h1.z, acc.z); acc.w = fmaf(p1.w, h1.w, acc.w);
            acc.x = fmaf(p2.x, h2.x, acc.x); acc.y = fmaf(p2.y, h2.y, acc.y);
            acc.z = fmaf(p2.z, h2.z, acc.z); acc.w = fmaf(p2.w, h2.w, acc.w);
            acc.x = fmaf(p3.x, h3.x, acc.x); acc.y = fmaf(p3.y, h3.y, acc.y);
            acc.z = fmaf(p3.z, h3.z, acc.z); acc.w = fmaf(p3.w, h3.w, acc.w);
            acc.x = fmaf(p4.x, h4.x, acc.x); acc.y = fmaf(p4.y, h4.y, acc.y);
            acc.z = fmaf(p4.z, h4.z, acc.z); acc.w = fmaf(p4.w, h4.w, acc.w);
            acc.x = fmaf(p5.x, h5.x, acc.x); acc.y = fmaf(p5.y, h5.y, acc.y);
            acc.z = fmaf(p5.z, h5.z, acc.z); acc.w = fmaf(p5.w, h5.w, acc.w);
            acc.x = fmaf(p6.x, h6.x, acc.x); acc.y = fmaf(p6.y, h6.y, acc.y);
            acc.z = fmaf(p6.z, h6.z, acc.z); acc.w = fmaf(p6.w, h6.w, acc.w);
            acc.x = fmaf(p7.x, h7.x, acc.x); acc.y = fmaf(p7.y, h7.y, acc.y);
            acc.z = fmaf(p7.z, h7.z, acc.z); acc.w = fmaf(p7.w, h7.w, acc.w);
        }
        __syncthreads();
    }
    float o = 0.25f * (acc.x / ssum.x + acc.y / ssum.y + acc.z / ssum.z + acc.w / ssum.w)
            + bias[lane];
    if (do_relu) o = fmaxf(o, 0.f);
    out[((size_t)node << 6) + lane] = o;
}

// ---------------- GRU input-side GEMM: giseq[t][r][192] = bih + x_t[r] @ Wih^T ----------------
// v3: W pinned register-resident (asm), launch_bounds(192,4), 3200 blocks,
// 2-row ILP pairs, float4 x loads.
// MODE 0: input gat2out [G][N][64] gathered (g=b*T+t, row=(b,n)).  MODE 1: input [T][4000][64] flat.
template <int MODE>
__global__ __launch_bounds__(192, 4) void gru_gi(
    const float* __restrict__ in, const float* __restrict__ Wih,
    const float* __restrict__ bih, float* __restrict__ giseq) {
    const int ROWS = 10;  // 3200 blocks * 10 = 32000 (t,row) pairs
    int j = threadIdx.x;  // 0..191
    float wrow[64];
#pragma unroll
    for (int f4 = 0; f4 < 16; ++f4) {
        float4 w = *(const float4*)(Wih + (size_t)j * 64 + f4 * 4);
        wrow[4 * f4 + 0] = w.x; wrow[4 * f4 + 1] = w.y;
        wrow[4 * f4 + 2] = w.z; wrow[4 * f4 + 3] = w.w;
    }
    PIN64_(wrow)
    float bj = bih[j];
    int q0 = blockIdx.x * ROWS;
    int t = q0 / NROWS;            // constant per block (NROWS % ROWS == 0)
    int r0 = q0 - t * NROWS;
    for (int rr = 0; rr < ROWS; rr += 2) {
        const float *xa, *xb;
        if (MODE == 0) {
            int ra = r0 + rr, rb = ra + 1;
            int ba = ra / NN, na = ra - ba * NN;
            int bb2 = rb / NN, nb = rb - bb2 * NN;
            xa = in + (((size_t)(ba * TT + t) * NN + na) << 6);
            xb = in + (((size_t)(bb2 * TT + t) * NN + nb) << 6);
        } else {
            xa = in + ((size_t)(q0 + rr) << 6);
            xb = xa + 64;
        }
        float acca = bj, accb = bj;
#pragma unroll
        for (int f4 = 0; f4 < 16; ++f4) {
            float4 a4 = *(const float4*)(xa + f4 * 4);
            float4 b4 = *(const float4*)(xb + f4 * 4);
            acca = fmaf(a4.x, wrow[4 * f4 + 0], acca);
            acca = fmaf(a4.y, wrow[4 * f4 + 1], acca);
            acca = fmaf(a4.z, wrow[4 * f4 + 2], acca);
            acca = fmaf(a4.w, wrow[4 * f4 + 3], acca);
            accb = fmaf(b4.x, wrow[4 * f4 + 0], accb);
            accb = fmaf(b4.y, wrow[4 * f4 + 1], accb);
            accb = fmaf(b4.z, wrow[4 * f4 + 2], accb);
            accb = fmaf(b4.w, wrow[4 * f4 + 3], accb);
        }
        giseq[(size_t)(q0 + rr) * 192 + j] = acca;
        giseq[(size_t)(q0 + rr + 1) * 192 + j] = accb;
    }
}

// ---------------- GRU recurrence v2 (Whh side only; gi precomputed) ----------------
// Thread ch owns the full gate triplet: Whh rows {ch, 64+ch, 128+ch} in 192 VGPRs.
// h-state in LDS, wave-private (wave w owns rows w*4..w*4+3) -> ZERO barriers.
// h reads are wave-uniform ds_read_b128 broadcasts (16 per row).
// LAYER 0: outseq = h1seq [T][4000][64] (store every t). LAYER 1: outseq = hT [4000][64].
template <int LAYER>
__global__ __launch_bounds__(128) void gru_rec(
    const float* __restrict__ giseq, const float* __restrict__ Whh,
    const float* __restrict__ bhh, float* __restrict__ outseq) {
    __shared__ float hs[8][64];       // 2 waves * 4 rows, wave-private regions
    int tid = threadIdx.x;
    int ch = tid & 63, w = tid >> 6;  // w in {0,1}
    float wr[64], wz[64], wn[64];
#pragma unroll
    for (int k4 = 0; k4 < 16; ++k4) {
        float4 a = *(const float4*)(Whh + (size_t)ch * 64 + k4 * 4);
        float4 b = *(const float4*)(Whh + (size_t)(64 + ch) * 64 + k4 * 4);
        float4 c = *(const float4*)(Whh + (size_t)(128 + ch) * 64 + k4 * 4);
        wr[4*k4+0] = a.x; wr[4*k4+1] = a.y; wr[4*k4+2] = a.z; wr[4*k4+3] = a.w;
        wz[4*k4+0] = b.x; wz[4*k4+1] = b.y; wz[4*k4+2] = b.z; wz[4*k4+3] = b.w;
        wn[4*k4+0] = c.x; wn[4*k4+1] = c.y; wn[4*k4+2] = c.z; wn[4*k4+3] = c.w;
    }
    float br = bhh[ch], bz = bhh[64 + ch], bn = bhh[128 + ch];
    int row0 = blockIdx.x * 8 + w * 4;
    float hprev[4];
#pragma unroll
    for (int r = 0; r < 4; ++r) { hs[w * 4 + r][ch] = 0.f; hprev[r] = 0.f; }

    for (int t = 0; t < TT; ++t) {
#pragma unroll
        for (int r = 0; r < 4; ++r) {
            int row = row0 + r;
            const float* gp = giseq + ((size_t)(t * NROWS + row)) * 192;
            float gir = gp[ch], giz = gp[64 + ch], gin = gp[128 + ch];
            float ar = br, az = bz, an = bn;
#pragma unroll
            for (int k4 = 0; k4 < 16; ++k4) {
                float4 h4 = *(const float4*)&hs[w * 4 + r][k4 * 4];  // broadcast
                ar = fmaf(h4.x, wr[4*k4+0], ar); ar = fmaf(h4.y, wr[4*k4+1], ar);
                ar = fmaf(h4.z, wr[4*k4+2], ar); ar = fmaf(h4.w, wr[4*k4+3], ar);
                az = fmaf(h4.x, wz[4*k4+0], az); az = fmaf(h4.y, wz[4*k4+1], az);
                az = fmaf(h4.z, wz[4*k4+2], az); az = fmaf(h4.w, wz[4*k4+3], az);
                an = fmaf(h4.x, wn[4*k4+0], an); an = fmaf(h4.y, wn[4*k4+1], an);
                an = fmaf(h4.z, wn[4*k4+2], an); an = fmaf(h4.w, wn[4*k4+3], an);
            }
            float rg = sigmoidf_(gir + ar);
            float zg = sigmoidf_(giz + az);
            float ng = tanhf_(gin + rg * an);
            float hnew = (1.f - zg) * ng + zg * hprev[r];
            hprev[r] = hnew;
            hs[w * 4 + r][ch] = hnew;   // same-wave LDS dep, compiler orders via lgkmcnt
            if (LAYER == 0)
                outseq[(((size_t)(t * NROWS + row)) << 6) + ch] = hnew;
        }
    }
    if (LAYER == 1) {
#pragma unroll
        for (int r = 0; r < 4; ++r)
            outseq[(((size_t)(row0 + r)) << 6) + ch] = hprev[r];
    }
}

// ---------------- final MLP ----------------
__global__ __launch_bounds__(64) void mlp_head(
    const float* __restrict__ hT, const float* __restrict__ pW1,
    const float* __restrict__ pb1, const float* __restrict__ pW2,
    const float* __restrict__ pb2, float* __restrict__ out) {
    int r = blockIdx.x, lane = threadIdx.x;
    __shared__ float hrow[64];
    __shared__ float mid[64];
    hrow[lane] = hT[((size_t)r << 6) + lane];
    __syncthreads();
    float acc = pb1[lane];
#pragma unroll
    for (int k = 0; k < 64; ++k) acc = fmaf(hrow[k], pW1[k * 64 + lane], acc);
    mid[lane] = fmaxf(acc, 0.f);
    __syncthreads();
    if (lane < 10) {
        float o = pb2[lane];
#pragma unroll
        for (int k = 0; k < 64; ++k) o = fmaf(mid[k], pW2[k * 10 + lane], o);
        out[(size_t)r * 10 + lane] = o;
    }
}

// ---------------- launch ----------------
extern "C" void kernel_launch(void* const* d_in, const int* in_sizes, int n_in,
                              void* d_out, int out_size, void* d_ws, size_t ws_size,
                              hipStream_t stream) {
    (void)in_sizes; (void)n_in; (void)out_size; (void)ws_size;
    const float* x    = (const float*)d_in[0];
    const int*   ei   = (const int*)d_in[1];
    const float* W1   = (const float*)d_in[3];
    const float* as1  = (const float*)d_in[4];
    const float* ad1  = (const float*)d_in[5];
    const float* b1   = (const float*)d_in[6];
    const float* W2   = (const float*)d_in[7];
    const float* as2  = (const float*)d_in[8];
    const float* ad2  = (const float*)d_in[9];
    const float* b2   = (const float*)d_in[10];
    const float* Wih0 = (const float*)d_in[13];
    const float* Whh0 = (const float*)d_in[14];
    const float* bih0 = (const float*)d_in[15];
    const float* bhh0 = (const float*)d_in[16];
    const float* Wih1 = (const float*)d_in[17];
    const float* Whh1 = (const float*)d_in[18];
    const float* bih1 = (const float*)d_in[19];
    const float* bhh1 = (const float*)d_in[20];
    const float* pW1  = (const float*)d_in[21];
    const float* pb1  = (const float*)d_in[22];
    const float* pW2  = (const float*)d_in[23];
    const float* pb2  = (const float*)d_in[24];
    float* out = (float*)d_out;

    // workspace layout (bytes); overlays noted
    char* ws = (char*)d_ws;
    float* hlin  = (float*)(ws + 0);           // 32,768,000  (overlay: giseq 24.58MB)
    float* giseq = hlin;
    float* asrc  = (float*)(ws + 32768000);    // 512,000     (overlay: hT 1MB spans asrc+adst)
    float* hT    = asrc;
    float* adst  = (float*)(ws + 33280000);    // 512,000
    float* gat1  = (float*)(ws + 33792000);    // 8,192,000   (overlay: h1seq)
    float* h1seq = gat1;
    float* gat2  = (float*)(ws + 41984000);    // 8,192,000
    int* counts  = (int*)(ws + 50176000);      // 128,000
    int* cursor  = (int*)(ws + 50304000);      // 128,000
    int* offs    = (int*)(ws + 50432000);      // 128,004 (padded to 128,256)
    int* csr     = (int*)(ws + 50560256);      // 2,176,000  -> total 52.7MB

    hipMemsetAsync(counts, 0, 2 * GN * sizeof(int), stream);  // counts + cursor (adjacent)

    dim3 egrid((E2 + 255) / 256, GG);
    count_edges<<<egrid, 256, 0, stream>>>(ei, counts);
    scan_offsets_pg<<<GG, 256, 0, stream>>>(counts, offs);
    scatter_edges<<<egrid, 256, 0, stream>>>(ei, offs, cursor, csr);

    gat_linear<0><<<GG * 50, 512, 0, stream>>>(x, W1, as1, ad1, hlin, asrc, adst);
    gat_edge<<<GN / 4, 256, 0, stream>>>(hlin, asrc, adst, offs, csr, b1, gat1, 1);
    gat_linear<1><<<GG * 50, 512, 0, stream>>>(gat1, W2, as2, ad2, hlin, asrc, adst);
    gat_edge<<<GN / 4, 256, 0, stream>>>(hlin, asrc, adst, offs, csr, b2, gat2, 0);

    gru_gi<0><<<3200, 192, 0, stream>>>(gat2, Wih0, bih0, giseq);
    gru_rec<0><<<500, 128, 0, stream>>>(giseq, Whh0, bhh0, h1seq);
    gru_gi<1><<<3200, 192, 0, stream>>>(h1seq, Wih1, bih1, giseq);
    gru_rec<1><<<500, 128, 0, stream>>>(giseq, Whh1, bhh1, hT);

    mlp_head<<<NROWS, 64, 0, stream>>>(hT, pW1, pb1, pW2, pb2, out);
}

// Round 8
// 416.609 us; speedup vs baseline: 1.9424x; 1.1080x over previous
//
#include <hip/hip_runtime.h>
#include <math.h>

// Problem constants
#define BB 4
#define NN 1000
#define TT 8
#define FF 64
#define HH 64
#define NHEADS 4
#define EE 16000
#define E2 17000          // EE + NN self-loops (EXACT per-graph edge total)
#define GG (BB*TT)        // 32 graphs
#define GN (GG*NN)        // 32000 (graph,node) pairs
#define NROWS (BB*NN)     // 4000 GRU rows

// ---------------- helpers ----------------
__device__ __forceinline__ float sigmoidf_(float x) {
    return 1.f / (1.f + __expf(-x));
}
__device__ __forceinline__ float tanhf_(float x) {
    x = fminf(fmaxf(x, -15.f), 15.f);
    float e = __expf(2.f * x);
    return (e - 1.f) / (e + 1.f);
}
__device__ __forceinline__ float leaky_(float x) {
    return (x > 0.f) ? x : 0.2f * x;
}

// ---------------- CSR build ----------------
__global__ void count_edges(const int* __restrict__ ei, int* __restrict__ counts) {
    int g = blockIdx.y;
    int e = blockIdx.x * 256 + threadIdx.x;
    if (e >= E2) return;
    int dst;
    if (e < EE) dst = ei[(size_t)g * 2 * EE + EE + e];
    else        dst = e - EE;   // self-loop
    atomicAdd(&counts[g * NN + dst], 1);
}

// Per-graph scan: each graph owns csr region [g*E2, (g+1)*E2); only a
// 1000-element scan per graph is needed. One 256-thread block per graph.
__global__ __launch_bounds__(256) void scan_offsets_pg(const int* __restrict__ counts,
                                                       int* __restrict__ offs) {
    __shared__ int tot[256];
    int g = blockIdx.x;
    int tid = threadIdx.x;
    int base = tid * 4;
    int c0 = 0, c1 = 0, c2 = 0, c3 = 0;
    if (base < NN) {
        int4 v = *(const int4*)(counts + (size_t)g * NN + base);  // 16B aligned (NN%4==0)
        c0 = v.x; c1 = v.y; c2 = v.z; c3 = v.w;
    }
    int s = c0 + c1 + c2 + c3;
    tot[tid] = s;
    __syncthreads();
    // Hillis-Steele inclusive scan over 256 partials
    for (int off = 1; off < 256; off <<= 1) {
        int y = (tid >= off) ? tot[tid - off] : 0;
        __syncthreads();
        tot[tid] += y;
        __syncthreads();
    }
    int run = g * E2 + tot[tid] - s;  // exclusive prefix + graph base
    if (base < NN) {
        int4 o;
        o.x = run; run += c0;
        o.y = run; run += c1;
        o.z = run; run += c2;
        o.w = run;
        *(int4*)(offs + (size_t)g * NN + base) = o;
    }
    if (g == 0 && tid == 0) offs[GN] = GG * E2;
}

__global__ void scatter_edges(const int* __restrict__ ei, const int* __restrict__ offs,
                              int* __restrict__ cursor, int* __restrict__ csr) {
    int g = blockIdx.y;
    int e = blockIdx.x * 256 + threadIdx.x;
    if (e >= E2) return;
    int src, dst;
    if (e < EE) {
        src = ei[(size_t)g * 2 * EE + e];
        dst = ei[(size_t)g * 2 * EE + EE + e];
    } else {
        src = dst = e - EE;
    }
    int i = g * NN + dst;
    int pos = offs[i] + atomicAdd(&cursor[i], 1);
    csr[pos] = src;
}

// Register pin (used by gru_gi; kept from R7 to avoid confounds there)
#define PIN64_(arr)                                        \
    _Pragma("unroll")                                      \
    for (int _pi = 0; _pi < 64; ++_pi)                     \
        asm volatile("" : "+v"((arr)[_pi]));

// ---------------- GAT linear (v2 FROZEN — R1-R7: every restructure regressed) ----------------
// v2 body: wcol strided loads, wave-uniform scalar x loads, ROWS=10. 42.3us,
// VALUBusy 40%, L2-latency-bound. Attempted: pin (no-op, VGPR stays 44),
// runtime loops (unrolled anyway), transposed W (uncoalesced, 54us), 4col/lane
// (write-allocate explosion, 247us), LDS W (occupancy collapse, 123us),
// LDS W+x (LDS-pipe-bound, 56us). Escape path if needed: MFMA split-bf16.
// hlin layout: [node][chan][head] (head fastest, float4 per chan)
// MODE 0: input is x [B,N,T,F] gathered per graph g=(b,t).  MODE 1: input [G,N,F] contiguous.
template <int MODE>
__global__ __launch_bounds__(256) void gat_linear(
    const float* __restrict__ in, const float* __restrict__ W,
    const float* __restrict__ att_s, const float* __restrict__ att_d,
    float* __restrict__ hlin, float* __restrict__ asrc, float* __restrict__ adst) {
    const int ROWS = 10;
    const int CH = NN / ROWS;  // 100 -> 3200 blocks
    int g = blockIdx.x / CH;
    int n0 = (blockIdx.x % CH) * ROWS;
    int tid = threadIdx.x;
    // W column into registers: W[f][tid]
    float wcol[FF];
#pragma unroll
    for (int f = 0; f < FF; ++f) wcol[f] = W[f * 256 + tid];
    int head = tid >> 6, lane = tid & 63;
    float as = att_s[head * HH + lane];
    float ad = att_d[head * HH + lane];
    int b = g / TT, t = g % TT;
    for (int r = 0; r < ROWS; ++r) {
        int n = n0 + r;
        const float* xrow;
        if (MODE == 0) xrow = in + (((size_t)(b * NN + n) * TT + t) * FF);
        else           xrow = in + ((size_t)(g * NN + n) * FF);
        float acc = 0.f;
#pragma unroll
        for (int f = 0; f < FF; ++f) acc = fmaf(xrow[f], wcol[f], acc);
        // transposed store: [node][chan=lane][head]
        hlin[((size_t)(g * NN + n) << 8) + (lane << 2) + head] = acc;
        float s1 = acc * as, s2 = acc * ad;
#pragma unroll
        for (int off = 32; off; off >>= 1) {
            s1 += __shfl_xor(s1, off, 64);
            s2 += __shfl_xor(s2, off, 64);
        }
        if (lane == 0) {
            asrc[(size_t)(g * NN + n) * NHEADS + head] = s1;
            adst[(size_t)(g * NN + n) * NHEADS + head] = s2;
        }
    }
}

// ---------------- GAT edge softmax + aggregation (v3: 8-way MLP phase B) ----------------
// One wave per destination node. Phase A computes per-edge weights into LDS
// (zero-filled beyond deg). Phase B rounds the edge count up to a multiple of
// 8 (padded edges: p=0, src=0 -> harmless) and issues 8 independent 1KB
// gathers per batch: MLP 1 -> 8 (R8: serial loop was latency-bound, L2 at
// 36% of ceiling, VALUBusy 33%).
__global__ __launch_bounds__(256) void gat_edge(
    const float* __restrict__ hlin, const float* __restrict__ asrc,
    const float* __restrict__ adst, const int* __restrict__ offs,
    const int* __restrict__ csr, const float* __restrict__ bias,
    float* __restrict__ out, int do_relu) {
    __shared__ float pbuf[4][64][4];   // [wave][edge-in-chunk][head]
    __shared__ int   sbuf[4][64];
    __shared__ int   degs[4];
    int tid = threadIdx.x;
    int lane = tid & 63, w = tid >> 6;
    // XCD swizzle: graph g -> XCD g%8 (consecutive blockIdx round-robins XCDs)
    int B = blockIdx.x;
    int x = B & 7, j = B >> 3;             // j in 0..999
    int graph = x + 8 * (j / 250);
    int node = graph * NN + ((j % 250) << 2) + w;
    int beg = offs[node], end = offs[node + 1];
    int deg = end - beg;
    if (lane == 0) degs[w] = deg;
    __syncthreads();
    int maxdeg = max(max(degs[0], degs[1]), max(degs[2], degs[3]));
    int nchunk = (maxdeg + 63) >> 6;

    float4 ad = *(const float4*)(adst + (size_t)node * 4);
    const float* asrc_g = asrc + (size_t)graph * NN * 4;
    const float* hg = hlin + ((size_t)graph * NN << 8);

    float4 acc = make_float4(0.f, 0.f, 0.f, 0.f);
    float4 ssum = make_float4(0.f, 0.f, 0.f, 0.f);
    for (int c = 0; c < nchunk; ++c) {
        int e0 = beg + (c << 6);
        int myedge = e0 + lane;
        float4 p = make_float4(0.f, 0.f, 0.f, 0.f);
        int src = 0;
        if (myedge < end) {
            src = csr[myedge];
            float4 a = *(const float4*)(asrc_g + (size_t)src * 4);
            p.x = __expf(leaky_(a.x + ad.x));
            p.y = __expf(leaky_(a.y + ad.y));
            p.z = __expf(leaky_(a.z + ad.z));
            p.w = __expf(leaky_(a.w + ad.w));
        }
        // butterfly sum of this chunk's weights
        float4 t = p;
#pragma unroll
        for (int off = 1; off < 64; off <<= 1) {
            t.x += __shfl_xor(t.x, off, 64);
            t.y += __shfl_xor(t.y, off, 64);
            t.z += __shfl_xor(t.z, off, 64);
            t.w += __shfl_xor(t.w, off, 64);
        }
        ssum.x += t.x; ssum.y += t.y; ssum.z += t.z; ssum.w += t.w;
        *(float4*)&pbuf[w][lane][0] = p;
        sbuf[w][lane] = src;
        __syncthreads();
        int cnt = end - e0;
        if (cnt > 64) cnt = 64;
        int cnt8 = (cnt + 7) & ~7;         // pad to x8: pbuf/sbuf zero-filled
        for (int e = 0; e < cnt8; e += 8) {
            float4 p0 = *(const float4*)&pbuf[w][e + 0][0];
            float4 p1 = *(const float4*)&pbuf[w][e + 1][0];
            float4 p2 = *(const float4*)&pbuf[w][e + 2][0];
            float4 p3 = *(const float4*)&pbuf[w][e + 3][0];
            float4 p4 = *(const float4*)&pbuf[w][e + 4][0];
            float4 p5 = *(const float4*)&pbuf[w][e + 5][0];
            float4 p6 = *(const float4*)&pbuf[w][e + 6][0];
            float4 p7 = *(const float4*)&pbuf[w][e + 7][0];
            int s0 = sbuf[w][e + 0], s1 = sbuf[w][e + 1];
            int s2 = sbuf[w][e + 2], s3 = sbuf[w][e + 3];
            int s4 = sbuf[w][e + 4], s5 = sbuf[w][e + 5];
            int s6 = sbuf[w][e + 6], s7 = sbuf[w][e + 7];
            int lo = lane << 2;
            float4 h0 = *(const float4*)(hg + (((size_t)s0) << 8) + lo);
            float4 h1 = *(const float4*)(hg + (((size_t)s1) << 8) + lo);
            float4 h2 = *(const float4*)(hg + (((size_t)s2) << 8) + lo);
            float4 h3 = *(const float4*)(hg + (((size_t)s3) << 8) + lo);
            float4 h4 = *(const float4*)(hg + (((size_t)s4) << 8) + lo);
            float4 h5 = *(const float4*)(hg + (((size_t)s5) << 8) + lo);
            float4 h6 = *(const float4*)(hg + (((size_t)s6) << 8) + lo);
            float4 h7 = *(const float4*)(hg + (((size_t)s7) << 8) + lo);
            acc.x = fmaf(p0.x, h0.x, acc.x); acc.y = fmaf(p0.y, h0.y, acc.y);
            acc.z = fmaf(p0.z, h0.z, acc.z); acc.w = fmaf(p0.w, h0.w, acc.w);
            acc.x = fmaf(p1.x, h1.x, acc.x); acc.y = fmaf(p1.y, h1.y, acc.y);
            acc.z = fmaf(p1.z, h1.z, acc.z); acc.w = fmaf(p1.w, h1.w, acc.w);
            acc.x = fmaf(p2.x, h2.x, acc.x); acc.y = fmaf(p2.y, h2.y, acc.y);
            acc.z = fmaf(p2.z, h2.z, acc.z); acc.w = fmaf(p2.w, h2.w, acc.w);
            acc.x = fmaf(p3.x, h3.x, acc.x); acc.y = fmaf(p3.y, h3.y, acc.y);
            acc.z = fmaf(p3.z, h3.z, acc.z); acc.w = fmaf(p3.w, h3.w, acc.w);
            acc.x = fmaf(p4.x, h4.x, acc.x); acc.y = fmaf(p4.y, h4.y, acc.y);
            acc.z = fmaf(p4.z, h4.z, acc.z); acc.w = fmaf(p4.w, h4.w, acc.w);
            acc.x = fmaf(p5.x, h5.x, acc.x); acc.y = fmaf(p5.y, h5.y, acc.y);
            acc.z = fmaf(p5.z, h5.z, acc.z); acc.w = fmaf(p5.w, h5.w, acc.w);
            acc.x = fmaf(p6.x, h6.x, acc.x); acc.y = fmaf(p6.y, h6.y, acc.y);
            acc.z = fmaf(p6.z, h6.z, acc.z); acc.w = fmaf(p6.w, h6.w, acc.w);
            acc.x = fmaf(p7.x, h7.x, acc.x); acc.y = fmaf(p7.y, h7.y, acc.y);
            acc.z = fmaf(p7.z, h7.z, acc.z); acc.w = fmaf(p7.w, h7.w, acc.w);
        }
        __syncthreads();
    }
    float o = 0.25f * (acc.x / ssum.x + acc.y / ssum.y + acc.z / ssum.z + acc.w / ssum.w)
            + bias[lane];
    if (do_relu) o = fmaxf(o, 0.f);
    out[((size_t)node << 6) + lane] = o;
}

// ---------------- GRU input-side GEMM: giseq[t][r][192] = bih + x_t[r] @ Wih^T ----------------
// v3: W pinned register-resident (asm), launch_bounds(192,4), 3200 blocks,
// 2-row ILP pairs, float4 x loads.
// MODE 0: input gat2out [G][N][64] gathered (g=b*T+t, row=(b,n)).  MODE 1: input [T][4000][64] flat.
template <int MODE>
__global__ __launch_bounds__(192, 4) void gru_gi(
    const float* __restrict__ in, const float* __restrict__ Wih,
    const float* __restrict__ bih, float* __restrict__ giseq) {
    const int ROWS = 10;  // 3200 blocks * 10 = 32000 (t,row) pairs
    int j = threadIdx.x;  // 0..191
    float wrow[64];
#pragma unroll
    for (int f4 = 0; f4 < 16; ++f4) {
        float4 w = *(const float4*)(Wih + (size_t)j * 64 + f4 * 4);
        wrow[4 * f4 + 0] = w.x; wrow[4 * f4 + 1] = w.y;
        wrow[4 * f4 + 2] = w.z; wrow[4 * f4 + 3] = w.w;
    }
    PIN64_(wrow)
    float bj = bih[j];
    int q0 = blockIdx.x * ROWS;
    int t = q0 / NROWS;            // constant per block (NROWS % ROWS == 0)
    int r0 = q0 - t * NROWS;
    for (int rr = 0; rr < ROWS; rr += 2) {
        const float *xa, *xb;
        if (MODE == 0) {
            int ra = r0 + rr, rb = ra + 1;
            int ba = ra / NN, na = ra - ba * NN;
            int bb2 = rb / NN, nb = rb - bb2 * NN;
            xa = in + (((size_t)(ba * TT + t) * NN + na) << 6);
            xb = in + (((size_t)(bb2 * TT + t) * NN + nb) << 6);
        } else {
            xa = in + ((size_t)(q0 + rr) << 6);
            xb = xa + 64;
        }
        float acca = bj, accb = bj;
#pragma unroll
        for (int f4 = 0; f4 < 16; ++f4) {
            float4 a4 = *(const float4*)(xa + f4 * 4);
            float4 b4 = *(const float4*)(xb + f4 * 4);
            acca = fmaf(a4.x, wrow[4 * f4 + 0], acca);
            acca = fmaf(a4.y, wrow[4 * f4 + 1], acca);
            acca = fmaf(a4.z, wrow[4 * f4 + 2], acca);
            acca = fmaf(a4.w, wrow[4 * f4 + 3], acca);
            accb = fmaf(b4.x, wrow[4 * f4 + 0], accb);
            accb = fmaf(b4.y, wrow[4 * f4 + 1], accb);
            accb = fmaf(b4.z, wrow[4 * f4 + 2], accb);
            accb = fmaf(b4.w, wrow[4 * f4 + 3], accb);
        }
        giseq[(size_t)(q0 + rr) * 192 + j] = acca;
        giseq[(size_t)(q0 + rr + 1) * 192 + j] = accb;
    }
}

// ---------------- GRU recurrence v3 (2 rows/wave, 1000 blocks) ----------------
// R7 change: v2 launched 500 blocks = 1000 waves ~= 1 wave/SIMD, but at 192
// weight-VGPRs the HW allows 2 waves/SIMD — we ran at HALF the allowed
// occupancy with 6144 dependent FMAs + 512 LDS reads per thread and no TLP
// to hide latency. Rows are independent: 1000 blocks x 2 rows/wave -> 2000
// waves = 2/SIMD (the VGPR cap). Weight L2 reload doubles to ~98MB (~3us
// aggregate) — cheap. Everything else identical.
// LAYER 0: outseq = h1seq [T][4000][64] (store every t). LAYER 1: outseq = hT [4000][64].
template <int LAYER>
__global__ __launch_bounds__(128) void gru_rec(
    const float* __restrict__ giseq, const float* __restrict__ Whh,
    const float* __restrict__ bhh, float* __restrict__ outseq) {
    __shared__ float hs[4][64];       // 2 waves * 2 rows, wave-private regions
    int tid = threadIdx.x;
    int ch = tid & 63, w = tid >> 6;  // w in {0,1}
    float wr[64], wz[64], wn[64];
#pragma unroll
    for (int k4 = 0; k4 < 16; ++k4) {
        float4 a = *(const float4*)(Whh + (size_t)ch * 64 + k4 * 4);
        float4 b = *(const float4*)(Whh + (size_t)(64 + ch) * 64 + k4 * 4);
        float4 c = *(const float4*)(Whh + (size_t)(128 + ch) * 64 + k4 * 4);
        wr[4*k4+0] = a.x; wr[4*k4+1] = a.y; wr[4*k4+2] = a.z; wr[4*k4+3] = a.w;
        wz[4*k4+0] = b.x; wz[4*k4+1] = b.y; wz[4*k4+2] = b.z; wz[4*k4+3] = b.w;
        wn[4*k4+0] = c.x; wn[4*k4+1] = c.y; wn[4*k4+2] = c.z; wn[4*k4+3] = c.w;
    }
    float br = bhh[ch], bz = bhh[64 + ch], bn = bhh[128 + ch];
    int row0 = blockIdx.x * 4 + w * 2;
    float hprev[2];
#pragma unroll
    for (int r = 0; r < 2; ++r) { hs[w * 2 + r][ch] = 0.f; hprev[r] = 0.f; }

    for (int t = 0; t < TT; ++t) {
#pragma unroll
        for (int r = 0; r < 2; ++r) {
            int row = row0 + r;
            const float* gp = giseq + ((size_t)(t * NROWS + row)) * 192;
            float gir = gp[ch], giz = gp[64 + ch], gin = gp[128 + ch];
            float ar = br, az = bz, an = bn;
#pragma unroll
            for (int k4 = 0; k4 < 16; ++k4) {
                float4 h4 = *(const float4*)&hs[w * 2 + r][k4 * 4];  // broadcast
                ar = fmaf(h4.x, wr[4*k4+0], ar); ar = fmaf(h4.y, wr[4*k4+1], ar);
                ar = fmaf(h4.z, wr[4*k4+2], ar); ar = fmaf(h4.w, wr[4*k4+3], ar);
                az = fmaf(h4.x, wz[4*k4+0], az); az = fmaf(h4.y, wz[4*k4+1], az);
                az = fmaf(h4.z, wz[4*k4+2], az); az = fmaf(h4.w, wz[4*k4+3], az);
                an = fmaf(h4.x, wn[4*k4+0], an); an = fmaf(h4.y, wn[4*k4+1], an);
                an = fmaf(h4.z, wn[4*k4+2], an); an = fmaf(h4.w, wn[4*k4+3], an);
            }
            float rg = sigmoidf_(gir + ar);
            float zg = sigmoidf_(giz + az);
            float ng = tanhf_(gin + rg * an);
            float hnew = (1.f - zg) * ng + zg * hprev[r];
            hprev[r] = hnew;
            hs[w * 2 + r][ch] = hnew;   // same-wave LDS dep, compiler orders via lgkmcnt
            if (LAYER == 0)
                outseq[(((size_t)(t * NROWS + row)) << 6) + ch] = hnew;
        }
    }
    if (LAYER == 1) {
#pragma unroll
        for (int r = 0; r < 2; ++r)
            outseq[(((size_t)(row0 + r)) << 6) + ch] = hprev[r];
    }
}

// ---------------- final MLP ----------------
__global__ __launch_bounds__(64) void mlp_head(
    const float* __restrict__ hT, const float* __restrict__ pW1,
    const float* __restrict__ pb1, const float* __restrict__ pW2,
    const float* __restrict__ pb2, float* __restrict__ out) {
    int r = blockIdx.x, lane = threadIdx.x;
    __shared__ float hrow[64];
    __shared__ float mid[64];
    hrow[lane] = hT[((size_t)r << 6) + lane];
    __syncthreads();
    float acc = pb1[lane];
#pragma unroll
    for (int k = 0; k < 64; ++k) acc = fmaf(hrow[k], pW1[k * 64 + lane], acc);
    mid[lane] = fmaxf(acc, 0.f);
    __syncthreads();
    if (lane < 10) {
        float o = pb2[lane];
#pragma unroll
        for (int k = 0; k < 64; ++k) o = fmaf(mid[k], pW2[k * 10 + lane], o);
        out[(size_t)r * 10 + lane] = o;
    }
}

// ---------------- launch ----------------
extern "C" void kernel_launch(void* const* d_in, const int* in_sizes, int n_in,
                              void* d_out, int out_size, void* d_ws, size_t ws_size,
                              hipStream_t stream) {
    (void)in_sizes; (void)n_in; (void)out_size; (void)ws_size;
    const float* x    = (const float*)d_in[0];
    const int*   ei   = (const int*)d_in[1];
    const float* W1   = (const float*)d_in[3];
    const float* as1  = (const float*)d_in[4];
    const float* ad1  = (const float*)d_in[5];
    const float* b1   = (const float*)d_in[6];
    const float* W2   = (const float*)d_in[7];
    const float* as2  = (const float*)d_in[8];
    const float* ad2  = (const float*)d_in[9];
    const float* b2   = (const float*)d_in[10];
    const float* Wih0 = (const float*)d_in[13];
    const float* Whh0 = (const float*)d_in[14];
    const float* bih0 = (const float*)d_in[15];
    const float* bhh0 = (const float*)d_in[16];
    const float* Wih1 = (const float*)d_in[17];
    const float* Whh1 = (const float*)d_in[18];
    const float* bih1 = (const float*)d_in[19];
    const float* bhh1 = (const float*)d_in[20];
    const float* pW1  = (const float*)d_in[21];
    const float* pb1  = (const float*)d_in[22];
    const float* pW2  = (const float*)d_in[23];
    const float* pb2  = (const float*)d_in[24];
    float* out = (float*)d_out;

    // workspace layout (bytes); overlays noted
    char* ws = (char*)d_ws;
    float* hlin  = (float*)(ws + 0);           // 32,768,000  (overlay: giseq 24.58MB)
    float* giseq = hlin;
    float* asrc  = (float*)(ws + 32768000);    // 512,000     (overlay: hT 1MB spans asrc+adst)
    float* hT    = asrc;
    float* adst  = (float*)(ws + 33280000);    // 512,000
    float* gat1  = (float*)(ws + 33792000);    // 8,192,000   (overlay: h1seq)
    float* h1seq = gat1;
    float* gat2  = (float*)(ws + 41984000);    // 8,192,000
    int* counts  = (int*)(ws + 50176000);      // 128,000
    int* cursor  = (int*)(ws + 50304000);      // 128,000
    int* offs    = (int*)(ws + 50432000);      // 128,004 (padded to 128,256)
    int* csr     = (int*)(ws + 50560256);      // 2,176,000  -> total 52.7MB

    hipMemsetAsync(counts, 0, 2 * GN * sizeof(int), stream);  // counts + cursor (adjacent)

    dim3 egrid((E2 + 255) / 256, GG);
    count_edges<<<egrid, 256, 0, stream>>>(ei, counts);
    scan_offsets_pg<<<GG, 256, 0, stream>>>(counts, offs);
    scatter_edges<<<egrid, 256, 0, stream>>>(ei, offs, cursor, csr);

    gat_linear<0><<<GG * 100, 256, 0, stream>>>(x, W1, as1, ad1, hlin, asrc, adst);
    gat_edge<<<GN / 4, 256, 0, stream>>>(hlin, asrc, adst, offs, csr, b1, gat1, 1);
    gat_linear<1><<<GG * 100, 256, 0, stream>>>(gat1, W2, as2, ad2, hlin, asrc, adst);
    gat_edge<<<GN / 4, 256, 0, stream>>>(hlin, asrc, adst, offs, csr, b2, gat2, 0);

    gru_gi<0><<<3200, 192, 0, stream>>>(gat2, Wih0, bih0, giseq);
    gru_rec<0><<<1000, 128, 0, stream>>>(giseq, Whh0, bhh0, h1seq);
    gru_gi<1><<<3200, 192, 0, stream>>>(h1seq, Wih1, bih1, giseq);
    gru_rec<1><<<1000, 128, 0, stream>>>(giseq, Whh1, bhh1, hT);

    mlp_head<<<NROWS, 64, 0, stream>>>(hT, pW1, pb1, pW2, pb2, out);
}